// Round 7
// baseline (796.879 us; speedup 1.0000x reference)
//
#include <hip/hip_runtime.h>
#include <stdint.h>

typedef unsigned short u16;
typedef __bf16 bf16x8 __attribute__((ext_vector_type(8)));
typedef float f32x4 __attribute__((ext_vector_type(4)));

#define SEQ   2048
#define EMBED 4096
#define KDIM  4096
#define NH    32
#define NKV   16
#define HD    128
#define KVW   2048   // N_KV_HEADS * HD

__device__ __forceinline__ float bf2f(u16 u) {
  union { uint32_t u; float f; } v; v.u = ((uint32_t)u) << 16; return v.f;
}
__device__ __forceinline__ u16 f2bf(float f) {
  union { float f; uint32_t u; } v; v.f = f;
  return (u16)((v.u + 0x7FFFu + ((v.u >> 16) & 1u)) >> 16);
}
__device__ __forceinline__ void g2l16(const u16* g, u16* l) {
  __builtin_amdgcn_global_load_lds(
      (const __attribute__((address_space(1))) uint32_t*)g,
      (__attribute__((address_space(3))) uint32_t*)l, 16, 0, 0);
}
// raw barrier with compiler memory fence (no waitcnt drain)
__device__ __forceinline__ void BAR() {
  asm volatile("" ::: "memory");
  __builtin_amdgcn_s_barrier();
  asm volatile("" ::: "memory");
}

// ---------------- x: f32 -> bf16, same layout ----------------
__global__ __launch_bounds__(256) void convert_x(
    const float* __restrict__ X, u16* __restrict__ Xb, int nquad) {
  for (int i = blockIdx.x * 256 + threadIdx.x; i < nquad;
       i += gridDim.x * 256) {
    float4 v = *(const float4*)(X + (size_t)i * 4);
    ushort4 o;
    o.x = f2bf(v.x); o.y = f2bf(v.y); o.z = f2bf(v.z); o.w = f2bf(v.w);
    *(ushort4*)(Xb + (size_t)i * 4) = o;
  }
}

// ---------------- transpose+convert: Wt[n][k] = bf16(W[k][n]) ----------------
__global__ __launch_bounds__(256) void transpose_cvt(
    const float* __restrict__ W, u16* __restrict__ Wt, int K, int N) {
  __shared__ u16 tile[64][68];
  const int t = threadIdx.x;
  const int n0 = blockIdx.x * 64, k0 = blockIdx.y * 64;
#pragma unroll
  for (int i = 0; i < 4; i++) {
    int c = i * 256 + t;
    int r = c >> 4, cq = c & 15;
    float4 v = *(const float4*)(W + (size_t)(k0 + r) * N + n0 + cq * 4);
    tile[r][cq * 4 + 0] = f2bf(v.x); tile[r][cq * 4 + 1] = f2bf(v.y);
    tile[r][cq * 4 + 2] = f2bf(v.z); tile[r][cq * 4 + 3] = f2bf(v.w);
  }
  __syncthreads();
#pragma unroll
  for (int i = 0; i < 4; i++) {
    int c = i * 256 + t;
    int rn = c >> 4, cq = c & 15;
    ushort4 v;
    v.x = tile[cq * 4 + 0][rn];
    v.y = tile[cq * 4 + 1][rn];
    v.z = tile[cq * 4 + 2][rn];
    v.w = tile[cq * 4 + 3][rn];
    *(ushort4*)(Wt + (size_t)(n0 + rn) * K + k0 + cq * 4) = v;
  }
}

// ================= 256x256 GEMM for QKV, reg-double-buffered pipeline =======
// 4 MFMA clusters/K-tile; fragment ds_reads issued >=1 cluster before use
// (compiler emits counted lgkmcnt); 2 barriers/K-tile at staging hazards;
// counted vmcnt. Depth-2 tile prefetch.
__global__ __launch_bounds__(512, 2) void gemm8_qkv(
    const u16* __restrict__ A,
    const u16* __restrict__ B0, const u16* __restrict__ B1,
    const u16* __restrict__ B2,
    u16* __restrict__ Qo, u16* __restrict__ Ko, u16* __restrict__ Vt) {
  __shared__ __align__(16) u16 As[2][256 * 64];
  __shared__ __align__(16) u16 Bs[2][256 * 64];
  const int t = threadIdx.x;
  const int lane = t & 63;
  const int w = t >> 6;
  const int wr = w >> 2;
  const int wc = w & 3;
  const int g = lane >> 4;
  const int l15 = lane & 15;
  const int NT = KDIM / 64;  // 64

  const int bid = blockIdx.x;
  const int swz = (bid & 7) * 32 + (bid >> 3);
  const int mb = swz & 7;
  const int nb = swz >> 3;
  const int m0 = mb * 256;

  const u16* Bt; int nrow0;
  if (nb < 16)      { Bt = B0; nrow0 = nb * 256; }
  else if (nb < 24) { Bt = B1; nrow0 = (nb - 16) * 256; }
  else              { Bt = B2; nrow0 = (nb - 24) * 256; }

  auto stA = [&](int buf, int kt, int h) {
#pragma unroll
    for (int i = 0; i < 2; i++) {
      int c = i * 512 + t;
      int row = c >> 3, sp = c & 7;
      int col = (sp ^ (row & 7)) << 3;
      g2l16(A + (size_t)(m0 + h * 128 + row) * KDIM + kt + col,
            &As[buf][h * 8192 + c * 8]);
    }
  };
  auto stB = [&](int buf, int kt, int h) {
#pragma unroll
    for (int i = 0; i < 2; i++) {
      int c = i * 512 + t;
      int row = c >> 3, sp = c & 7;
      int col = (sp ^ (row & 7)) << 3;
      g2l16(Bt + (size_t)(nrow0 + h * 128 + row) * KDIM + kt + col,
            &Bs[buf][h * 8192 + c * 8]);
    }
  };

  f32x4 acc[8][4];
#pragma unroll
  for (int i = 0; i < 8; i++)
#pragma unroll
    for (int j = 0; j < 4; j++) acc[i][j] = (f32x4){0.f, 0.f, 0.f, 0.f};

  // fragment readers (fixed lane->LDS map, swizzled)
  auto rdA0 = [&](const u16* S, bf16x8 (&d)[2][4]) {
#pragma unroll
    for (int kk = 0; kk < 2; kk++)
#pragma unroll
      for (int mi = 0; mi < 4; mi++) {
        int r = wr * 128 + mi * 16 + l15;
        int sl = (kk * 4 + g) ^ (r & 7);
        d[kk][mi] = *(const bf16x8*)(S + r * 64 + sl * 8);
      }
  };
  auto rdA1 = [&](const u16* S, bf16x8 (&d)[2][4]) {
#pragma unroll
    for (int kk = 0; kk < 2; kk++)
#pragma unroll
      for (int mi = 0; mi < 4; mi++) {
        int r = wr * 128 + 64 + mi * 16 + l15;
        int sl = (kk * 4 + g) ^ (r & 7);
        d[kk][mi] = *(const bf16x8*)(S + r * 64 + sl * 8);
      }
  };
  auto rdB0 = [&](const u16* S, bf16x8 (&d)[2][2]) {
#pragma unroll
    for (int kk = 0; kk < 2; kk++)
#pragma unroll
      for (int ni = 0; ni < 2; ni++) {
        int r = wc * 64 + ni * 16 + l15;
        int sl = (kk * 4 + g) ^ (r & 7);
        d[kk][ni] = *(const bf16x8*)(S + r * 64 + sl * 8);
      }
  };
  auto rdB1 = [&](const u16* S, bf16x8 (&d)[2][2]) {
#pragma unroll
    for (int kk = 0; kk < 2; kk++)
#pragma unroll
      for (int ni = 0; ni < 2; ni++) {
        int r = wc * 64 + (ni + 2) * 16 + l15;
        int sl = (kk * 4 + g) ^ (r & 7);
        d[kk][ni] = *(const bf16x8*)(S + r * 64 + sl * 8);
      }
  };
  auto mmQ = [&](bf16x8 (&Af)[2][4], bf16x8 (&Bf)[2][2], int mo, int no) {
    __builtin_amdgcn_s_setprio(1);
#pragma unroll
    for (int mi = 0; mi < 4; mi++)
#pragma unroll
      for (int ni = 0; ni < 2; ni++)
#pragma unroll
        for (int kk = 0; kk < 2; kk++)
          acc[mi + mo][ni + no] = __builtin_amdgcn_mfma_f32_16x16x32_bf16(
              Af[kk][mi], Bf[kk][ni], acc[mi + mo][ni + no], 0, 0, 0);
    __builtin_amdgcn_s_setprio(0);
  };

  // prologue: stage tiles 0,1; wait tile 0; read tile0 a0,b0
  stA(0, 0, 0); stA(0, 0, 1); stB(0, 0, 0); stB(0, 0, 1);
  stA(1, 64, 0); stA(1, 64, 1); stB(1, 64, 0); stB(1, 64, 1);
  asm volatile("s_waitcnt vmcnt(8)" ::: "memory");
  BAR();

  bf16x8 a0X[2][4], b0X[2][2], a0Y[2][4], b0Y[2][2];
  rdA0(As[0], a0X); rdB0(Bs[0], b0X);

  auto body = [&](int ti, const u16* CA, const u16* CB,
                  const u16* NA, const u16* NB,
                  bf16x8 (&a0)[2][4], bf16x8 (&b0)[2][2],
                  bf16x8 (&a0n)[2][4], bf16x8 (&b0n)[2][2], int sb) {
    bf16x8 a1[2][4], b1[2][2];
    const int kt2 = (ti + 2) * 64;
    // P0: issue a1; MFMA Q00 = a0*b0 (read last iter -> latency hidden)
    rdA1(CA, a1);
    __builtin_amdgcn_sched_barrier(0);
    mmQ(a0, b0, 0, 0);
    // P1: issue b1; MFMA Q10 = a1*b0 (a1 issued one cluster ago)
    rdB1(CB, b1);
    __builtin_amdgcn_sched_barrier(0);
    mmQ(a1, b0, 4, 0);
    // B1: A(t+1) landed (vmcnt(4) leaves B(t+1) in flight);
    //     all waves consumed a0,a1,b0 -> A-staging safe
    asm volatile("s_waitcnt vmcnt(4)" ::: "memory");
    BAR();
    // P2: stage A(t+2); issue a0n (from other buffer); MFMA Q11 = a1*b1
    if (ti + 2 < NT) { stA(sb, kt2, 0); stA(sb, kt2, 1); }
    if (ti + 1 < NT) rdA0(NA, a0n);
    __builtin_amdgcn_sched_barrier(0);
    mmQ(a1, b1, 4, 2);
    // B2: B(t+1) landed (leave A(t+2) in flight); b1 consumed -> B-staging safe
    if (ti + 2 < NT) asm volatile("s_waitcnt vmcnt(4)" ::: "memory");
    else             asm volatile("s_waitcnt vmcnt(0)" ::: "memory");
    BAR();
    // P3: stage B(t+2); issue b0n; MFMA Q01 = a0*b1
    if (ti + 2 < NT) { stB(sb, kt2, 0); stB(sb, kt2, 1); }
    if (ti + 1 < NT) rdB0(NB, b0n);
    __builtin_amdgcn_sched_barrier(0);
    mmQ(a0, b1, 0, 2);
  };

  for (int ti = 0; ti < NT; ti += 2) {
    body(ti,     As[0], Bs[0], As[1], Bs[1], a0X, b0X, a0Y, b0Y, 0);
    body(ti + 1, As[1], Bs[1], As[0], Bs[0], a0Y, b0Y, a0X, b0X, 1);
  }

#pragma unroll
  for (int mi = 0; mi < 8; mi++) {
#pragma unroll
    for (int ni = 0; ni < 4; ni++) {
      int rowg = m0 + wr * 128 + mi * 16 + g * 4;
      int ncol = nb * 256 + wc * 64 + ni * 16 + l15;
      if (nb < 16) {
#pragma unroll
        for (int r = 0; r < 4; r++)
          Qo[(size_t)(rowg + r) * EMBED + ncol] = f2bf(acc[mi][ni][r]);
      } else if (nb < 24) {
        int nc = ncol - 4096;
#pragma unroll
        for (int r = 0; r < 4; r++)
          Ko[(size_t)(rowg + r) * KVW + nc] = f2bf(acc[mi][ni][r]);
      } else {
        int nc = ncol - 6144;  // kv_head*128 + d
        ushort4 v;
        v.x = f2bf(acc[mi][ni][0]); v.y = f2bf(acc[mi][ni][1]);
        v.z = f2bf(acc[mi][ni][2]); v.w = f2bf(acc[mi][ni][3]);
        *(ushort4*)(Vt + (size_t)nc * SEQ + rowg) = v;
      }
    }
  }
}

// ================= out-proj: BM=128 x BN=256, same pipeline, f32 out ========
__global__ __launch_bounds__(512, 2) void gemm8_op(
    const u16* __restrict__ A, const u16* __restrict__ Bt,
    float* __restrict__ Cf) {
  __shared__ __align__(16) u16 As[2][128 * 64];
  __shared__ __align__(16) u16 Bs[2][256 * 64];
  const int t = threadIdx.x;
  const int lane = t & 63;
  const int w = t >> 6;
  const int wr = w >> 2;
  const int wc = w & 3;
  const int g = lane >> 4;
  const int l15 = lane & 15;
  const int NT = KDIM / 64;

  const int bid = blockIdx.x;
  const int swz = (bid & 7) * 32 + (bid >> 3);
  const int mb = swz & 15;
  const int nb = swz >> 4;
  const int m0 = mb * 128;
  const int nrow0 = nb * 256;

  auto stA = [&](int buf, int kt) {
#pragma unroll
    for (int i = 0; i < 1; i++) { }
#pragma unroll
    for (int i = 0; i < 2; i++) {
      int c = i * 512 + t;
      int row = c >> 3, sp = c & 7;
      int col = (sp ^ (row & 7)) << 3;
      g2l16(A + (size_t)(m0 + row) * KDIM + kt + col, &As[buf][c * 8]);
    }
  };
  auto stB = [&](int buf, int kt) {
#pragma unroll
    for (int i = 0; i < 4; i++) {
      int c = i * 512 + t;
      int row = c >> 3, sp = c & 7;
      int col = (sp ^ (row & 7)) << 3;
      g2l16(Bt + (size_t)(nrow0 + row) * KDIM + kt + col, &Bs[buf][c * 8]);
    }
  };

  f32x4 acc[4][4];
#pragma unroll
  for (int i = 0; i < 4; i++)
#pragma unroll
    for (int j = 0; j < 4; j++) acc[i][j] = (f32x4){0.f, 0.f, 0.f, 0.f};

  auto rdA = [&](const u16* S, bf16x8 (&d)[2][4]) {
#pragma unroll
    for (int kk = 0; kk < 2; kk++)
#pragma unroll
      for (int mi = 0; mi < 4; mi++) {
        int r = wr * 64 + mi * 16 + l15;
        int sl = (kk * 4 + g) ^ (r & 7);
        d[kk][mi] = *(const bf16x8*)(S + r * 64 + sl * 8);
      }
  };
  auto rdB0 = [&](const u16* S, bf16x8 (&d)[2][2]) {
#pragma unroll
    for (int kk = 0; kk < 2; kk++)
#pragma unroll
      for (int ni = 0; ni < 2; ni++) {
        int r = wc * 64 + ni * 16 + l15;
        int sl = (kk * 4 + g) ^ (r & 7);
        d[kk][ni] = *(const bf16x8*)(S + r * 64 + sl * 8);
      }
  };
  auto rdB1 = [&](const u16* S, bf16x8 (&d)[2][2]) {
#pragma unroll
    for (int kk = 0; kk < 2; kk++)
#pragma unroll
      for (int ni = 0; ni < 2; ni++) {
        int r = wc * 64 + (ni + 2) * 16 + l15;
        int sl = (kk * 4 + g) ^ (r & 7);
        d[kk][ni] = *(const bf16x8*)(S + r * 64 + sl * 8);
      }
  };
  auto mmQ = [&](bf16x8 (&Af)[2][4], bf16x8 (&Bf)[2][2], int no) {
    __builtin_amdgcn_s_setprio(1);
#pragma unroll
    for (int mi = 0; mi < 4; mi++)
#pragma unroll
      for (int ni = 0; ni < 2; ni++)
#pragma unroll
        for (int kk = 0; kk < 2; kk++)
          acc[mi][ni + no] = __builtin_amdgcn_mfma_f32_16x16x32_bf16(
              Af[kk][mi], Bf[kk][ni], acc[mi][ni + no], 0, 0, 0);
    __builtin_amdgcn_s_setprio(0);
  };

  stA(0, 0); stB(0, 0);
  stA(1, 64); stB(1, 64);
  asm volatile("s_waitcnt vmcnt(6)" ::: "memory");
  BAR();

  bf16x8 aX[2][4], b0X[2][2], aY[2][4], b0Y[2][2];
  rdA(As[0], aX); rdB0(Bs[0], b0X);

  auto body = [&](int ti, const u16* CB, const u16* NA, const u16* NB,
                  bf16x8 (&a)[2][4], bf16x8 (&b0)[2][2],
                  bf16x8 (&an)[2][4], bf16x8 (&b0n)[2][2], int sb) {
    bf16x8 b1[2][2];
    const int kt2 = (ti + 2) * 64;
    // P0: issue b1; MFMA Q0 = a*b0
    rdB1(CB, b1);
    __builtin_amdgcn_sched_barrier(0);
    mmQ(a, b0, 0);
    // B1: A(t+1) landed (vmcnt(4) leaves B(t+1)); a,b0 consumed by all
    asm volatile("s_waitcnt vmcnt(4)" ::: "memory");
    BAR();
    // P1: stage A(t+2); issue an; MFMA Q1 = a*b1
    if (ti + 2 < NT) stA(sb, kt2);
    if (ti + 1 < NT) rdA(NA, an);
    __builtin_amdgcn_sched_barrier(0);
    mmQ(a, b1, 2);
    // B2: B(t+1) landed (leave A(t+2)); b1 consumed by all
    if (ti + 2 < NT) asm volatile("s_waitcnt vmcnt(2)" ::: "memory");
    else             asm volatile("s_waitcnt vmcnt(0)" ::: "memory");
    BAR();
    // P2: stage B(t+2); issue b0n
    if (ti + 2 < NT) stB(sb, kt2);
    if (ti + 1 < NT) rdB0(NB, b0n);
  };

  for (int ti = 0; ti < NT; ti += 2) {
    body(ti,     Bs[0], As[1], Bs[1], aX, b0X, aY, b0Y, 0);
    body(ti + 1, Bs[1], As[0], Bs[0], aY, b0Y, aX, b0X, 1);
  }

#pragma unroll
  for (int mi = 0; mi < 4; mi++)
#pragma unroll
    for (int ni = 0; ni < 4; ni++) {
      int rowg = m0 + wr * 64 + mi * 16 + g * 4;
      int ncol = nb * 256 + wc * 64 + ni * 16 + l15;
#pragma unroll
      for (int r = 0; r < 4; r++)
        Cf[(size_t)(rowg + r) * 4096 + ncol] = acc[mi][ni][r];
    }
}

// ---------------- RoPE (in place) on Q [2048][4096] and K [2048][2048] ----
__global__ __launch_bounds__(256) void rope_kernel(
    u16* __restrict__ Q, u16* __restrict__ Kb,
    const float* __restrict__ freqs, const int* __restrict__ start_pos) {
  const int sp = start_pos[0];
  const float qscale = 0.08838834764831845f;  // 1/sqrt(128)
  const int total_q = SEQ * EMBED / 2;
  const int total_k = SEQ * KVW / 2;
  const int total = total_q + total_k;
  for (int idx = blockIdx.x * 256 + threadIdx.x; idx < total;
       idx += gridDim.x * 256) {
    u16* buf; int row, pi; bool isq = idx < total_q;
    if (isq) { row = idx >> 11; pi = idx & 2047; buf = Q + (size_t)row * EMBED; }
    else { int j = idx - total_q; row = j >> 10; pi = j & 1023; buf = Kb + (size_t)row * KVW; }
    int i = pi & 63;
    float2 cs = *(const float2*)(freqs + (size_t)(sp + row) * 128 + i * 2);
    float c = cs.x, s = cs.y;
    ushort2 tv = *(ushort2*)(buf + pi * 2);
    float t0 = bf2f(tv.x), t1 = bf2f(tv.y);
    float o0 = t0 * c - t1 * s;
    float o1 = t0 * s + t1 * c;
    if (isq) { o0 *= qscale; o1 *= qscale; }
    ushort2 o; o.x = f2bf(o0); o.y = f2bf(o1);
    *(ushort2*)(buf + pi * 2) = o;
  }
}

// ---------------- flash attention, causal, GQA ----------------
// Swapped QK^T (mfma(K,Q)) -> lane owns one q-row: softmax is 2 shfl deep.
__global__ __launch_bounds__(256, 4) void attn_kernel(
    const u16* __restrict__ Q, const u16* __restrict__ Kb,
    const u16* __restrict__ Vt, u16* __restrict__ O) {
  __shared__ __align__(16) u16 KV[16384];   // K: [0,8192) 64x128, V: [8192,..) 128x64
  __shared__ u16 Ps[4][16 * 72];

  const int t = threadIdx.x;
  const int lane = t & 63;
  const int w = t >> 6;
  const int g = lane >> 4;
  const int l15 = lane & 15;
  const int bid = blockIdx.x;
  const int qb = 31 - (bid >> 5);
  const int h = bid & 31;
  const int hk = h >> 1;

  auto stageK = [&](int kv) {
#pragma unroll
    for (int i = 0; i < 4; i++) {
      int c = i * 256 + t;
      int row = c >> 4, spp = c & 15;
      int col = ((spp ^ (row & 7)) << 3);
      g2l16(Kb + (size_t)(kv * 64 + row) * KVW + hk * HD + col, &KV[c * 8]);
    }
  };
  auto stageV = [&](int kv) {
#pragma unroll
    for (int i = 0; i < 4; i++) {
      int c = i * 256 + t;
      int row = c >> 3, spp = c & 7;
      int col = ((spp ^ (row & 7)) << 3);
      g2l16(Vt + (size_t)(hk * HD + row) * SEQ + kv * 64 + col,
            &KV[8192 + c * 8]);
    }
  };

#pragma unroll
  for (int i = 0; i < 4; i++) {
    int c = i * 256 + t;
    int row = c >> 4, spp = c & 15;
    int col = ((spp ^ (row & 7)) << 3);
    g2l16(Q + (size_t)(qb * 64 + row) * EMBED + h * HD + col, &KV[c * 8]);
  }
  asm volatile("s_waitcnt vmcnt(0)" ::: "memory");
  __builtin_amdgcn_s_barrier();

  bf16x8 qf[4];
  {
    int r = w * 16 + l15;
#pragma unroll
    for (int kk = 0; kk < 4; kk++) {
      int ps = (kk * 4 + g) ^ (r & 7);
      qf[kk] = *(const bf16x8*)(&KV[r * 128 + ps * 8]);
    }
  }
  asm volatile("s_waitcnt lgkmcnt(0)" ::: "memory");
  __builtin_amdgcn_s_barrier();

  f32x4 oacc[8];
#pragma unroll
  for (int i = 0; i < 8; i++) oacc[i] = (f32x4){0.f, 0.f, 0.f, 0.f};
  float mrow = -1e30f, lrow = 0.f;
  const int qg = qb * 64 + w * 16 + l15;

  for (int kv = 0; kv <= qb; kv++) {
    stageK(kv); stageV(kv);
    asm volatile("s_waitcnt vmcnt(0)" ::: "memory");
    __builtin_amdgcn_s_barrier();

    f32x4 sfragT[4];
    __builtin_amdgcn_s_setprio(1);
#pragma unroll
    for (int ni = 0; ni < 4; ni++) {
      f32x4 s = (f32x4){0.f, 0.f, 0.f, 0.f};
      int r = ni * 16 + l15;
#pragma unroll
      for (int kk = 0; kk < 4; kk++) {
        int ps = (kk * 4 + g) ^ (r & 7);
        bf16x8 a = *(const bf16x8*)(&KV[r * 128 + ps * 8]);
        s = __builtin_amdgcn_mfma_f32_16x16x32_bf16(a, qf[kk], s, 0, 0, 0);
      }
      sfragT[ni] = s;
    }
    __builtin_amdgcn_s_setprio(0);

    if (kv == qb) {
#pragma unroll
      for (int ni = 0; ni < 4; ni++) {
        int colg = kv * 64 + ni * 16 + g * 4;
#pragma unroll
        for (int r = 0; r < 4; r++)
          if (colg + r > qg) sfragT[ni][r] = -1e30f;
      }
    }

    float m16 = sfragT[0][0];
#pragma unroll
    for (int ni = 0; ni < 4; ni++)
#pragma unroll
      for (int r = 0; r < 4; r++) m16 = fmaxf(m16, sfragT[ni][r]);
    m16 = fmaxf(m16, __shfl_xor(m16, 16));
    m16 = fmaxf(m16, __shfl_xor(m16, 32));
    float mnew = fmaxf(mrow, m16);
    float sc = __expf(mrow - mnew);
    mrow = mnew;

    float rsum = 0.f;
#pragma unroll
    for (int ni = 0; ni < 4; ni++) {
#pragma unroll
      for (int r = 0; r < 4; r++) {
        float p = __expf(sfragT[ni][r] - mrow);
        rsum += p;
        Ps[w][l15 * 72 + ni * 16 + g * 4 + r] = f2bf(p);
      }
    }
    rsum += __shfl_xor(rsum, 16);
    rsum += __shfl_xor(rsum, 32);
    lrow = lrow * sc + rsum;

    float scr[4];
#pragma unroll
    for (int r = 0; r < 4; r++) scr[r] = __shfl(sc, g * 4 + r, 64);
#pragma unroll
    for (int nf = 0; nf < 8; nf++)
#pragma unroll
      for (int r = 0; r < 4; r++) oacc[nf][r] *= scr[r];

    asm volatile("s_waitcnt lgkmcnt(0)" ::: "memory");

    bf16x8 pa[2];
#pragma unroll
    for (int kk = 0; kk < 2; kk++)
      pa[kk] = *(const bf16x8*)(&Ps[w][l15 * 72 + kk * 32 + g * 8]);
    __builtin_amdgcn_s_setprio(1);
#pragma unroll
    for (int nf = 0; nf < 8; nf++) {
      int r = nf * 16 + l15;
#pragma unroll
      for (int kk = 0; kk < 2; kk++) {
        int ps = (kk * 4 + g) ^ (r & 7);
        bf16x8 b = *(const bf16x8*)(&KV[8192 + r * 64 + ps * 8]);
        oacc[nf] = __builtin_amdgcn_mfma_f32_16x16x32_bf16(pa[kk], b, oacc[nf], 0, 0, 0);
      }
    }
    __builtin_amdgcn_s_setprio(0);
    __builtin_amdgcn_s_barrier();
  }

  float lr[4];
#pragma unroll
  for (int r = 0; r < 4; r++) lr[r] = __shfl(lrow, g * 4 + r, 64);
#pragma unroll
  for (int nf = 0; nf < 8; nf++) {
#pragma unroll
    for (int r = 0; r < 4; r++) {
      int rowg = qb * 64 + w * 16 + g * 4 + r;
      float v = oacc[nf][r] / lr[r];
      O[(size_t)rowg * EMBED + h * HD + nf * 16 + l15] = f2bf(v);
    }
  }
}

extern "C" void kernel_launch(void* const* d_in, const int* in_sizes, int n_in,
                              void* d_out, int out_size, void* d_ws, size_t ws_size,
                              hipStream_t stream) {
  const float* x  = (const float*)d_in[0];
  const float* fc = (const float*)d_in[1];
  const float* wq = (const float*)d_in[2];
  const float* wk = (const float*)d_in[3];
  const float* wv = (const float*)d_in[4];
  const float* wo = (const float*)d_in[5];
  const int* sp = (const int*)d_in[6];

  char* ws = (char*)d_ws;
  u16* wqT = (u16*)(ws);                      // bf16 [4096][4096]
  u16* wkT = (u16*)(ws + 33554432ull);        // bf16 [2048][4096]
  u16* wvT = (u16*)(ws + 50331648ull);        // bf16 [2048][4096]
  u16* woT = (u16*)(ws + 67108864ull);        // bf16 [4096][4096]
  u16* xb  = (u16*)(ws + 100663296ull);       // bf16 [2048][4096]
  u16* Qb  = (u16*)(ws + 117440512ull);       // bf16 [2048][4096]
  u16* Kb  = (u16*)(ws + 134217728ull);       // bf16 [2048][2048]
  u16* Vt  = (u16*)(ws + 142606336ull);       // bf16 [2048][2048]
  u16* Ob  = (u16*)(ws + 150994944ull);       // bf16 [2048][4096]

  convert_x<<<dim3(2048), 256, 0, stream>>>(x, xb, SEQ * EMBED / 4);
  transpose_cvt<<<dim3(64, 64), 256, 0, stream>>>(wq, wqT, 4096, 4096);
  transpose_cvt<<<dim3(32, 64), 256, 0, stream>>>(wk, wkT, 4096, 2048);
  transpose_cvt<<<dim3(32, 64), 256, 0, stream>>>(wv, wvT, 4096, 2048);
  transpose_cvt<<<dim3(64, 64), 256, 0, stream>>>(wo, woT, 4096, 4096);

  gemm8_qkv<<<dim3(256), 512, 0, stream>>>(xb, wqT, wkT, wvT, Qb, Kb, Vt);
  rope_kernel<<<dim3(2048), 256, 0, stream>>>(Qb, Kb, fc, sp);
  attn_kernel<<<dim3(1024), 256, 0, stream>>>(Qb, Kb, Vt, Ob);
  gemm8_op<<<dim3(256), 512, 0, stream>>>(Ob, woT, (float*)d_out);
}

// Round 8
// 386.222 us; speedup vs baseline: 2.0633x; 2.0633x over previous
//
#include <hip/hip_runtime.h>
#include <stdint.h>

typedef unsigned short u16;
typedef __bf16 bf16x8 __attribute__((ext_vector_type(8)));
typedef float f32x4 __attribute__((ext_vector_type(4)));

#define SEQ   2048
#define EMBED 4096
#define KDIM  4096
#define NH    32
#define NKV   16
#define HD    128
#define KVW   2048   // N_KV_HEADS * HD

__device__ __forceinline__ float bf2f(u16 u) {
  union { uint32_t u; float f; } v; v.u = ((uint32_t)u) << 16; return v.f;
}
__device__ __forceinline__ u16 f2bf(float f) {
  union { float f; uint32_t u; } v; v.f = f;
  return (u16)((v.u + 0x7FFFu + ((v.u >> 16) & 1u)) >> 16);
}
__device__ __forceinline__ void g2l16(const u16* g, u16* l) {
  __builtin_amdgcn_global_load_lds(
      (const __attribute__((address_space(1))) uint32_t*)g,
      (__attribute__((address_space(3))) uint32_t*)l, 16, 0, 0);
}
__device__ __forceinline__ void BAR() {
  asm volatile("" ::: "memory");
  __builtin_amdgcn_s_barrier();
  asm volatile("" ::: "memory");
}

// ---------------- x: f32 -> bf16, same layout ----------------
__global__ __launch_bounds__(256) void convert_x(
    const float* __restrict__ X, u16* __restrict__ Xb, int nquad) {
  for (int i = blockIdx.x * 256 + threadIdx.x; i < nquad;
       i += gridDim.x * 256) {
    float4 v = *(const float4*)(X + (size_t)i * 4);
    ushort4 o;
    o.x = f2bf(v.x); o.y = f2bf(v.y); o.z = f2bf(v.z); o.w = f2bf(v.w);
    *(ushort4*)(Xb + (size_t)i * 4) = o;
  }
}

// ---------------- transpose+convert: Wt[n][k] = bf16(W[k][n]) ----------------
__global__ __launch_bounds__(256) void transpose_cvt(
    const float* __restrict__ W, u16* __restrict__ Wt, int K, int N) {
  __shared__ u16 tile[64][68];
  const int t = threadIdx.x;
  const int n0 = blockIdx.x * 64, k0 = blockIdx.y * 64;
#pragma unroll
  for (int i = 0; i < 4; i++) {
    int c = i * 256 + t;
    int r = c >> 4, cq = c & 15;
    float4 v = *(const float4*)(W + (size_t)(k0 + r) * N + n0 + cq * 4);
    tile[r][cq * 4 + 0] = f2bf(v.x); tile[r][cq * 4 + 1] = f2bf(v.y);
    tile[r][cq * 4 + 2] = f2bf(v.z); tile[r][cq * 4 + 3] = f2bf(v.w);
  }
  __syncthreads();
#pragma unroll
  for (int i = 0; i < 4; i++) {
    int c = i * 256 + t;
    int rn = c >> 4, cq = c & 15;
    ushort4 v;
    v.x = tile[cq * 4 + 0][rn];
    v.y = tile[cq * 4 + 1][rn];
    v.z = tile[cq * 4 + 2][rn];
    v.w = tile[cq * 4 + 3][rn];
    *(ushort4*)(Wt + (size_t)(n0 + rn) * K + k0 + cq * 4) = v;
  }
}

// ================= 256x256 GEMM for QKV: 1-barrier/K-tile pipeline ==========
// Per iter: vmcnt(0); BAR; stage t+1 -> buf^1; read all 24 frags from buf[cur];
// lgkmcnt(0); 64 MFMA. Single-copy fragments (~240 VGPR, no spill at cap 512;
// occupancy fixed at 1 block/CU by 128 KB LDS anyway).
__global__ __launch_bounds__(512, 1) void gemm8_qkv(
    const u16* __restrict__ A,
    const u16* __restrict__ B0, const u16* __restrict__ B1,
    const u16* __restrict__ B2,
    u16* __restrict__ Qo, u16* __restrict__ Ko, u16* __restrict__ Vt) {
  __shared__ __align__(16) u16 As[2][256 * 64];
  __shared__ __align__(16) u16 Bs[2][256 * 64];
  const int t = threadIdx.x;
  const int lane = t & 63;
  const int w = t >> 6;
  const int wr = w >> 2;
  const int wc = w & 3;
  const int g = lane >> 4;
  const int l15 = lane & 15;
  const int NT = KDIM / 64;  // 64

  const int bid = blockIdx.x;
  const int swz = (bid & 7) * 32 + (bid >> 3);
  const int mb = swz & 7;
  const int nb = swz >> 3;
  const int m0 = mb * 256;

  const u16* Bt; int nrow0;
  if (nb < 16)      { Bt = B0; nrow0 = nb * 256; }
  else if (nb < 24) { Bt = B1; nrow0 = (nb - 16) * 256; }
  else              { Bt = B2; nrow0 = (nb - 24) * 256; }

  auto stA = [&](int buf, int kt, int h) {
#pragma unroll
    for (int i = 0; i < 2; i++) {
      int c = i * 512 + t;
      int row = c >> 3, sp = c & 7;
      int col = (sp ^ (row & 7)) << 3;
      g2l16(A + (size_t)(m0 + h * 128 + row) * KDIM + kt + col,
            &As[buf][h * 8192 + c * 8]);
    }
  };
  auto stB = [&](int buf, int kt, int h) {
#pragma unroll
    for (int i = 0; i < 2; i++) {
      int c = i * 512 + t;
      int row = c >> 3, sp = c & 7;
      int col = (sp ^ (row & 7)) << 3;
      g2l16(Bt + (size_t)(nrow0 + h * 128 + row) * KDIM + kt + col,
            &Bs[buf][h * 8192 + c * 8]);
    }
  };

  f32x4 acc[8][4];
#pragma unroll
  for (int i = 0; i < 8; i++)
#pragma unroll
    for (int j = 0; j < 4; j++) acc[i][j] = (f32x4){0.f, 0.f, 0.f, 0.f};

  auto mmQ = [&](bf16x8 (&Af)[2][4], bf16x8 (&Bf)[2][2], int mo, int no) {
    __builtin_amdgcn_s_setprio(1);
#pragma unroll
    for (int mi = 0; mi < 4; mi++)
#pragma unroll
      for (int ni = 0; ni < 2; ni++)
#pragma unroll
        for (int kk = 0; kk < 2; kk++)
          acc[mi + mo][ni + no] = __builtin_amdgcn_mfma_f32_16x16x32_bf16(
              Af[kk][mi], Bf[kk][ni], acc[mi + mo][ni + no], 0, 0, 0);
    __builtin_amdgcn_s_setprio(0);
  };

  // prologue: stage tile 0
  stA(0, 0, 0); stA(0, 0, 1); stB(0, 0, 0); stB(0, 0, 1);

  for (int ti = 0; ti < NT; ++ti) {
    const int cur = ti & 1;
    const u16* Asc = As[cur];
    const u16* Bsc = Bs[cur];
    const int kt1 = (ti + 1) * 64;

    asm volatile("s_waitcnt vmcnt(0)" ::: "memory");  // tile t landed
    BAR();
    // stage t+1 into other buffer (reads of t-1 from it drained pre-barrier)
    if (ti + 1 < NT) {
      stA(cur ^ 1, kt1, 0); stA(cur ^ 1, kt1, 1);
      stB(cur ^ 1, kt1, 0); stB(cur ^ 1, kt1, 1);
    }
    // read all fragments of tile t
    bf16x8 a0[2][4], a1[2][4], b0[2][2], b1[2][2];
#pragma unroll
    for (int kk = 0; kk < 2; kk++)
#pragma unroll
      for (int mi = 0; mi < 4; mi++) {
        int r0 = wr * 128 + mi * 16 + l15;
        int s0 = (kk * 4 + g) ^ (r0 & 7);
        a0[kk][mi] = *(const bf16x8*)(Asc + r0 * 64 + s0 * 8);
        int r1 = r0 + 64;
        int s1 = (kk * 4 + g) ^ (r1 & 7);
        a1[kk][mi] = *(const bf16x8*)(Asc + r1 * 64 + s1 * 8);
      }
#pragma unroll
    for (int kk = 0; kk < 2; kk++)
#pragma unroll
      for (int ni = 0; ni < 2; ni++) {
        int r0 = wc * 64 + ni * 16 + l15;
        int s0 = (kk * 4 + g) ^ (r0 & 7);
        b0[kk][ni] = *(const bf16x8*)(Bsc + r0 * 64 + s0 * 8);
        int r1 = wc * 64 + (ni + 2) * 16 + l15;
        int s1 = (kk * 4 + g) ^ (r1 & 7);
        b1[kk][ni] = *(const bf16x8*)(Bsc + r1 * 64 + s1 * 8);
      }
    asm volatile("s_waitcnt lgkmcnt(0)" ::: "memory");
    __builtin_amdgcn_sched_barrier(0);
    mmQ(a0, b0, 0, 0);
    mmQ(a1, b0, 4, 0);
    mmQ(a1, b1, 4, 2);
    mmQ(a0, b1, 0, 2);
  }

#pragma unroll
  for (int mi = 0; mi < 8; mi++) {
#pragma unroll
    for (int ni = 0; ni < 4; ni++) {
      int rowg = m0 + wr * 128 + mi * 16 + g * 4;
      int ncol = nb * 256 + wc * 64 + ni * 16 + l15;
      if (nb < 16) {
#pragma unroll
        for (int r = 0; r < 4; r++)
          Qo[(size_t)(rowg + r) * EMBED + ncol] = f2bf(acc[mi][ni][r]);
      } else if (nb < 24) {
        int nc = ncol - 4096;
#pragma unroll
        for (int r = 0; r < 4; r++)
          Ko[(size_t)(rowg + r) * KVW + nc] = f2bf(acc[mi][ni][r]);
      } else {
        int nc = ncol - 6144;  // kv_head*128 + d
        ushort4 v;
        v.x = f2bf(acc[mi][ni][0]); v.y = f2bf(acc[mi][ni][1]);
        v.z = f2bf(acc[mi][ni][2]); v.w = f2bf(acc[mi][ni][3]);
        *(ushort4*)(Vt + (size_t)nc * SEQ + rowg) = v;
      }
    }
  }
}

// ================= out-proj: BM=128 x BN=256, 2-phase/K-tile, f32 out ======
// (round-6 version, unchanged — known good)
__global__ __launch_bounds__(512, 2) void gemm8_op(
    const u16* __restrict__ A, const u16* __restrict__ Bt,
    float* __restrict__ Cf) {
  __shared__ __align__(16) u16 As[2][128 * 64];
  __shared__ __align__(16) u16 Bs[2][256 * 64];
  const int t = threadIdx.x;
  const int lane = t & 63;
  const int w = t >> 6;
  const int wr = w >> 2;
  const int wc = w & 3;
  const int g = lane >> 4;
  const int l15 = lane & 15;

  const int bid = blockIdx.x;
  const int swz = (bid & 7) * 32 + (bid >> 3);
  const int mb = swz & 15;
  const int nb = swz >> 4;
  const int m0 = mb * 128;
  const int nrow0 = nb * 256;

  auto stageA = [&](int buf, int kt) {
#pragma unroll
    for (int i = 0; i < 2; i++) {
      int c = i * 512 + t;
      int row = c >> 3, sp = c & 7;
      int col = (sp ^ (row & 7)) << 3;
      g2l16(A + (size_t)(m0 + row) * KDIM + kt + col, &As[buf][c * 8]);
    }
  };
  auto stageB = [&](int buf, int kt) {
#pragma unroll
    for (int i = 0; i < 4; i++) {
      int c = i * 512 + t;
      int row = c >> 3, sp = c & 7;
      int col = (sp ^ (row & 7)) << 3;
      g2l16(Bt + (size_t)(nrow0 + row) * KDIM + kt + col, &Bs[buf][c * 8]);
    }
  };

  f32x4 acc[4][4];
#pragma unroll
  for (int i = 0; i < 4; i++)
#pragma unroll
    for (int j = 0; j < 4; j++) acc[i][j] = (f32x4){0.f, 0.f, 0.f, 0.f};

  stageA(0, 0); stageB(0, 0);
  stageA(1, 64); stageB(1, 64);
  asm volatile("s_waitcnt vmcnt(6)" ::: "memory");
  __builtin_amdgcn_s_barrier();

  const int NT = KDIM / 64;
  for (int ti = 0; ti < NT; ++ti) {
    const int cur = ti & 1;
    const u16* Asc = As[cur];
    const u16* Bsc = Bs[cur];
    const int ktn2 = (ti + 2) * 64;
    bf16x8 a[2][4], b0[2][2], b1[2][2];

#pragma unroll
    for (int kk = 0; kk < 2; kk++)
#pragma unroll
      for (int mi = 0; mi < 4; mi++) {
        int r = wr * 64 + mi * 16 + l15;
        int slot = (kk * 4 + g) ^ (r & 7);
        a[kk][mi] = *(const bf16x8*)(Asc + r * 64 + slot * 8);
      }
#pragma unroll
    for (int kk = 0; kk < 2; kk++)
#pragma unroll
      for (int ni = 0; ni < 2; ni++) {
        int r = wc * 64 + ni * 16 + l15;
        int slot = (kk * 4 + g) ^ (r & 7);
        b0[kk][ni] = *(const bf16x8*)(Bsc + r * 64 + slot * 8);
      }
#pragma unroll
    for (int kk = 0; kk < 2; kk++)
#pragma unroll
      for (int ni = 0; ni < 2; ni++) {
        int r = wc * 64 + (ni + 2) * 16 + l15;
        int slot = (kk * 4 + g) ^ (r & 7);
        b1[kk][ni] = *(const bf16x8*)(Bsc + r * 64 + slot * 8);
      }
    __builtin_amdgcn_s_barrier();
    asm volatile("s_waitcnt lgkmcnt(0)" ::: "memory");
    __builtin_amdgcn_sched_barrier(0);
    __builtin_amdgcn_s_setprio(1);
#pragma unroll
    for (int mi = 0; mi < 4; mi++)
#pragma unroll
      for (int ni = 0; ni < 2; ni++)
#pragma unroll
        for (int kk = 0; kk < 2; kk++)
          acc[mi][ni] = __builtin_amdgcn_mfma_f32_16x16x32_bf16(
              a[kk][mi], b0[kk][ni], acc[mi][ni], 0, 0, 0);
    __builtin_amdgcn_s_setprio(0);
    __builtin_amdgcn_s_barrier();

    if (ti + 2 < NT) { stageA(cur, ktn2); stageB(cur, ktn2); }
    __builtin_amdgcn_s_barrier();
    __builtin_amdgcn_s_setprio(1);
#pragma unroll
    for (int mi = 0; mi < 4; mi++)
#pragma unroll
      for (int ni = 0; ni < 2; ni++)
#pragma unroll
        for (int kk = 0; kk < 2; kk++)
          acc[mi][ni + 2] = __builtin_amdgcn_mfma_f32_16x16x32_bf16(
              a[kk][mi], b1[kk][ni], acc[mi][ni + 2], 0, 0, 0);
    __builtin_amdgcn_s_setprio(0);
    if (ti + 2 < NT)      asm volatile("s_waitcnt vmcnt(6)" ::: "memory");
    else if (ti + 1 < NT) asm volatile("s_waitcnt vmcnt(0)" ::: "memory");
    __builtin_amdgcn_s_barrier();
  }

#pragma unroll
  for (int mi = 0; mi < 4; mi++)
#pragma unroll
    for (int ni = 0; ni < 4; ni++) {
      int rowg = m0 + wr * 64 + mi * 16 + g * 4;
      int ncol = nb * 256 + wc * 64 + ni * 16 + l15;
#pragma unroll
      for (int r = 0; r < 4; r++)
        Cf[(size_t)(rowg + r) * 4096 + ncol] = acc[mi][ni][r];
    }
}

// ---------------- RoPE (in place) on Q [2048][4096] and K [2048][2048] ----
__global__ __launch_bounds__(256) void rope_kernel(
    u16* __restrict__ Q, u16* __restrict__ Kb,
    const float* __restrict__ freqs, const int* __restrict__ start_pos) {
  const int sp = start_pos[0];
  const float qscale = 0.08838834764831845f;  // 1/sqrt(128)
  const int total_q = SEQ * EMBED / 2;
  const int total_k = SEQ * KVW / 2;
  const int total = total_q + total_k;
  for (int idx = blockIdx.x * 256 + threadIdx.x; idx < total;
       idx += gridDim.x * 256) {
    u16* buf; int row, pi; bool isq = idx < total_q;
    if (isq) { row = idx >> 11; pi = idx & 2047; buf = Q + (size_t)row * EMBED; }
    else { int j = idx - total_q; row = j >> 10; pi = j & 1023; buf = Kb + (size_t)row * KVW; }
    int i = pi & 63;
    float2 cs = *(const float2*)(freqs + (size_t)(sp + row) * 128 + i * 2);
    float c = cs.x, s = cs.y;
    ushort2 tv = *(ushort2*)(buf + pi * 2);
    float t0 = bf2f(tv.x), t1 = bf2f(tv.y);
    float o0 = t0 * c - t1 * s;
    float o1 = t0 * s + t1 * c;
    if (isq) { o0 *= qscale; o1 *= qscale; }
    ushort2 o; o.x = f2bf(o0); o.y = f2bf(o1);
    *(ushort2*)(buf + pi * 2) = o;
  }
}

// ---------------- flash attention: 2 heads per block (shared K/V) ----------
// Swapped QK^T; both heads of one kv-group share K/V staging AND the
// K/V fragment ds_reads. Grid: 512 = 32 qb x 16 hk, qb descending.
__global__ __launch_bounds__(256, 2) void attn_kernel(
    const u16* __restrict__ Q, const u16* __restrict__ Kb,
    const u16* __restrict__ Vt, u16* __restrict__ O) {
  __shared__ __align__(16) u16 KV[16384];   // K: [0,8192) 64x128, V: [8192,..) 128x64
  __shared__ u16 Ps[4][16 * 72];

  const int t = threadIdx.x;
  const int lane = t & 63;
  const int w = t >> 6;
  const int g = lane >> 4;
  const int l15 = lane & 15;
  const int bid = blockIdx.x;
  const int qb = 31 - (bid >> 4);
  const int hk = bid & 15;
  const int hA = hk * 2, hB = hk * 2 + 1;

  auto stageK = [&](int kv) {
#pragma unroll
    for (int i = 0; i < 4; i++) {
      int c = i * 256 + t;
      int row = c >> 4, spp = c & 15;
      int col = ((spp ^ (row & 7)) << 3);
      g2l16(Kb + (size_t)(kv * 64 + row) * KVW + hk * HD + col, &KV[c * 8]);
    }
  };
  auto stageV = [&](int kv) {
#pragma unroll
    for (int i = 0; i < 4; i++) {
      int c = i * 256 + t;
      int row = c >> 3, spp = c & 7;
      int col = ((spp ^ (row & 7)) << 3);
      g2l16(Vt + (size_t)(hk * HD + row) * SEQ + kv * 64 + col,
            &KV[8192 + c * 8]);
    }
  };

  // stage Q_A into K slot, Q_B into V slot; read both; release
#pragma unroll
  for (int i = 0; i < 4; i++) {
    int c = i * 256 + t;
    int row = c >> 4, spp = c & 15;
    int col = ((spp ^ (row & 7)) << 3);
    g2l16(Q + (size_t)(qb * 64 + row) * EMBED + hA * HD + col, &KV[c * 8]);
    g2l16(Q + (size_t)(qb * 64 + row) * EMBED + hB * HD + col,
          &KV[8192 + c * 8]);
  }
  asm volatile("s_waitcnt vmcnt(0)" ::: "memory");
  __builtin_amdgcn_s_barrier();

  bf16x8 qfA[4], qfB[4];
  {
    int r = w * 16 + l15;
#pragma unroll
    for (int kk = 0; kk < 4; kk++) {
      int ps = (kk * 4 + g) ^ (r & 7);
      qfA[kk] = *(const bf16x8*)(&KV[r * 128 + ps * 8]);
      qfB[kk] = *(const bf16x8*)(&KV[8192 + r * 128 + ps * 8]);
    }
  }
  asm volatile("s_waitcnt lgkmcnt(0)" ::: "memory");
  __builtin_amdgcn_s_barrier();

  f32x4 oA[8], oB[8];
#pragma unroll
  for (int i = 0; i < 8; i++) {
    oA[i] = (f32x4){0.f, 0.f, 0.f, 0.f};
    oB[i] = (f32x4){0.f, 0.f, 0.f, 0.f};
  }
  float mA = -1e30f, lA = 0.f, mB = -1e30f, lB = 0.f;
  const int qg = qb * 64 + w * 16 + l15;

  for (int kv = 0; kv <= qb; kv++) {
    stageK(kv); stageV(kv);
    asm volatile("s_waitcnt vmcnt(0)" ::: "memory");
    __builtin_amdgcn_s_barrier();

    // S^T for both heads, K-fragments shared
    f32x4 sA[4], sB[4];
    __builtin_amdgcn_s_setprio(1);
#pragma unroll
    for (int ni = 0; ni < 4; ni++) {
      f32x4 xA = (f32x4){0.f, 0.f, 0.f, 0.f};
      f32x4 xB = (f32x4){0.f, 0.f, 0.f, 0.f};
      int r = ni * 16 + l15;
#pragma unroll
      for (int kk = 0; kk < 4; kk++) {
        int ps = (kk * 4 + g) ^ (r & 7);
        bf16x8 a = *(const bf16x8*)(&KV[r * 128 + ps * 8]);
        xA = __builtin_amdgcn_mfma_f32_16x16x32_bf16(a, qfA[kk], xA, 0, 0, 0);
        xB = __builtin_amdgcn_mfma_f32_16x16x32_bf16(a, qfB[kk], xB, 0, 0, 0);
      }
      sA[ni] = xA; sB[ni] = xB;
    }
    __builtin_amdgcn_s_setprio(0);

    if (kv == qb) {
#pragma unroll
      for (int ni = 0; ni < 4; ni++) {
        int colg = kv * 64 + ni * 16 + g * 4;
#pragma unroll
        for (int r = 0; r < 4; r++)
          if (colg + r > qg) { sA[ni][r] = -1e30f; sB[ni][r] = -1e30f; }
      }
    }

    // ---- softmax + P write + pa read, head A ----
    bf16x8 paA[2], paB[2];
    {
      float m16 = sA[0][0];
#pragma unroll
      for (int ni = 0; ni < 4; ni++)
#pragma unroll
        for (int r = 0; r < 4; r++) m16 = fmaxf(m16, sA[ni][r]);
      m16 = fmaxf(m16, __shfl_xor(m16, 16));
      m16 = fmaxf(m16, __shfl_xor(m16, 32));
      float mnew = fmaxf(mA, m16);
      float sc = __expf(mA - mnew);
      mA = mnew;
      float rsum = 0.f;
#pragma unroll
      for (int ni = 0; ni < 4; ni++)
#pragma unroll
        for (int r = 0; r < 4; r++) {
          float p = __expf(sA[ni][r] - mA);
          rsum += p;
          Ps[w][l15 * 72 + ni * 16 + g * 4 + r] = f2bf(p);
        }
      rsum += __shfl_xor(rsum, 16);
      rsum += __shfl_xor(rsum, 32);
      lA = lA * sc + rsum;
      float scr[4];
#pragma unroll
      for (int r = 0; r < 4; r++) scr[r] = __shfl(sc, g * 4 + r, 64);
#pragma unroll
      for (int nf = 0; nf < 8; nf++)
#pragma unroll
        for (int r = 0; r < 4; r++) oA[nf][r] *= scr[r];
      asm volatile("s_waitcnt lgkmcnt(0)" ::: "memory");
#pragma unroll
      for (int kk = 0; kk < 2; kk++)
        paA[kk] = *(const bf16x8*)(&Ps[w][l15 * 72 + kk * 32 + g * 8]);
      asm volatile("s_waitcnt lgkmcnt(0)" ::: "memory");  // paA read before B overwrites
    }
    // ---- softmax + P write + pa read, head B ----
    {
      float m16 = sB[0][0];
#pragma unroll
      for (int ni = 0; ni < 4; ni++)
#pragma unroll
        for (int r = 0; r < 4; r++) m16 = fmaxf(m16, sB[ni][r]);
      m16 = fmaxf(m16, __shfl_xor(m16, 16));
      m16 = fmaxf(m16, __shfl_xor(m16, 32));
      float mnew = fmaxf(mB, m16);
      float sc = __expf(mB - mnew);
      mB = mnew;
      float rsum = 0.f;
#pragma unroll
      for (int ni = 0; ni < 4; ni++)
#pragma unroll
        for (int r = 0; r < 4; r++) {
          float p = __expf(sB[ni][r] - mB);
          rsum += p;
          Ps[w][l15 * 72 + ni * 16 + g * 4 + r] = f2bf(p);
        }
      rsum += __shfl_xor(rsum, 16);
      rsum += __shfl_xor(rsum, 32);
      lB = lB * sc + rsum;
      float scr[4];
#pragma unroll
      for (int r = 0; r < 4; r++) scr[r] = __shfl(sc, g * 4 + r, 64);
#pragma unroll
      for (int nf = 0; nf < 8; nf++)
#pragma unroll
        for (int r = 0; r < 4; r++) oB[nf][r] *= scr[r];
      asm volatile("s_waitcnt lgkmcnt(0)" ::: "memory");
#pragma unroll
      for (int kk = 0; kk < 2; kk++)
        paB[kk] = *(const bf16x8*)(&Ps[w][l15 * 72 + kk * 32 + g * 8]);
    }

    // ---- PV for both heads, V-fragments shared ----
    __builtin_amdgcn_s_setprio(1);
#pragma unroll
    for (int nf = 0; nf < 8; nf++) {
      int r = nf * 16 + l15;
#pragma unroll
      for (int kk = 0; kk < 2; kk++) {
        int ps = (kk * 4 + g) ^ (r & 7);
        bf16x8 b = *(const bf16x8*)(&KV[8192 + r * 64 + ps * 8]);
        oA[nf] = __builtin_amdgcn_mfma_f32_16x16x32_bf16(paA[kk], b, oA[nf], 0, 0, 0);
        oB[nf] = __builtin_amdgcn_mfma_f32_16x16x32_bf16(paB[kk], b, oB[nf], 0, 0, 0);
      }
    }
    __builtin_amdgcn_s_setprio(0);
    __builtin_amdgcn_s_barrier();
  }

  float lrA[4], lrB[4];
#pragma unroll
  for (int r = 0; r < 4; r++) {
    lrA[r] = __shfl(lA, g * 4 + r, 64);
    lrB[r] = __shfl(lB, g * 4 + r, 64);
  }
#pragma unroll
  for (int nf = 0; nf < 8; nf++) {
#pragma unroll
    for (int r = 0; r < 4; r++) {
      int rowg = qb * 64 + w * 16 + g * 4 + r;
      O[(size_t)rowg * EMBED + hA * HD + nf * 16 + l15] = f2bf(oA[nf][r] / lrA[r]);
      O[(size_t)rowg * EMBED + hB * HD + nf * 16 + l15] = f2bf(oB[nf][r] / lrB[r]);
    }
  }
}

extern "C" void kernel_launch(void* const* d_in, const int* in_sizes, int n_in,
                              void* d_out, int out_size, void* d_ws, size_t ws_size,
                              hipStream_t stream) {
  const float* x  = (const float*)d_in[0];
  const float* fc = (const float*)d_in[1];
  const float* wq = (const float*)d_in[2];
  const float* wk = (const float*)d_in[3];
  const float* wv = (const float*)d_in[4];
  const float* wo = (const float*)d_in[5];
  const int* sp = (const int*)d_in[6];

  char* ws = (char*)d_ws;
  u16* wqT = (u16*)(ws);                      // bf16 [4096][4096]
  u16* wkT = (u16*)(ws + 33554432ull);        // bf16 [2048][4096]
  u16* wvT = (u16*)(ws + 50331648ull);        // bf16 [2048][4096]
  u16* woT = (u16*)(ws + 67108864ull);        // bf16 [4096][4096]
  u16* xb  = (u16*)(ws + 100663296ull);       // bf16 [2048][4096]
  u16* Qb  = (u16*)(ws + 117440512ull);       // bf16 [2048][4096]
  u16* Kb  = (u16*)(ws + 134217728ull);       // bf16 [2048][2048]
  u16* Vt  = (u16*)(ws + 142606336ull);       // bf16 [2048][2048]
  u16* Ob  = (u16*)(ws + 150994944ull);       // bf16 [2048][4096]

  convert_x<<<dim3(2048), 256, 0, stream>>>(x, xb, SEQ * EMBED / 4);
  transpose_cvt<<<dim3(64, 64), 256, 0, stream>>>(wq, wqT, 4096, 4096);
  transpose_cvt<<<dim3(32, 64), 256, 0, stream>>>(wk, wkT, 4096, 2048);
  transpose_cvt<<<dim3(32, 64), 256, 0, stream>>>(wv, wvT, 4096, 2048);
  transpose_cvt<<<dim3(64, 64), 256, 0, stream>>>(wo, woT, 4096, 4096);

  gemm8_qkv<<<dim3(256), 512, 0, stream>>>(xb, wqT, wkT, wvT, Qb, Kb, Vt);
  rope_kernel<<<dim3(2048), 256, 0, stream>>>(Qb, Kb, fc, sp);
  attn_kernel<<<dim3(512), 256, 0, stream>>>(Qb, Kb, Vt, Ob);
  gemm8_op<<<dim3(256), 512, 0, stream>>>(Ob, woT, (float*)d_out);
}

// Round 9
// 380.828 us; speedup vs baseline: 2.0925x; 1.0142x over previous
//
#include <hip/hip_runtime.h>
#include <stdint.h>

typedef unsigned short u16;
typedef __bf16 bf16x8 __attribute__((ext_vector_type(8)));
typedef float f32x4 __attribute__((ext_vector_type(4)));

#define SEQ   2048
#define EMBED 4096
#define KDIM  4096
#define NH    32
#define NKV   16
#define HD    128
#define KVW   2048   // N_KV_HEADS * HD

__device__ __forceinline__ float bf2f(u16 u) {
  union { uint32_t u; float f; } v; v.u = ((uint32_t)u) << 16; return v.f;
}
__device__ __forceinline__ u16 f2bf(float f) {
  union { float f; uint32_t u; } v; v.f = f;
  return (u16)((v.u + 0x7FFFu + ((v.u >> 16) & 1u)) >> 16);
}
__device__ __forceinline__ void g2l16(const u16* g, u16* l) {
  __builtin_amdgcn_global_load_lds(
      (const __attribute__((address_space(1))) uint32_t*)g,
      (__attribute__((address_space(3))) uint32_t*)l, 16, 0, 0);
}
__device__ __forceinline__ void BAR() {
  asm volatile("" ::: "memory");
  __builtin_amdgcn_s_barrier();
  asm volatile("" ::: "memory");
}

// ---------------- x: f32 -> bf16, same layout ----------------
__global__ __launch_bounds__(256) void convert_x(
    const float* __restrict__ X, u16* __restrict__ Xb, int nquad) {
  for (int i = blockIdx.x * 256 + threadIdx.x; i < nquad;
       i += gridDim.x * 256) {
    float4 v = *(const float4*)(X + (size_t)i * 4);
    ushort4 o;
    o.x = f2bf(v.x); o.y = f2bf(v.y); o.z = f2bf(v.z); o.w = f2bf(v.w);
    *(ushort4*)(Xb + (size_t)i * 4) = o;
  }
}

// ---------------- transpose+convert: Wt[n][k] = bf16(W[k][n]) ----------------
__global__ __launch_bounds__(256) void transpose_cvt(
    const float* __restrict__ W, u16* __restrict__ Wt, int K, int N) {
  __shared__ u16 tile[64][68];
  const int t = threadIdx.x;
  const int n0 = blockIdx.x * 64, k0 = blockIdx.y * 64;
#pragma unroll
  for (int i = 0; i < 4; i++) {
    int c = i * 256 + t;
    int r = c >> 4, cq = c & 15;
    float4 v = *(const float4*)(W + (size_t)(k0 + r) * N + n0 + cq * 4);
    tile[r][cq * 4 + 0] = f2bf(v.x); tile[r][cq * 4 + 1] = f2bf(v.y);
    tile[r][cq * 4 + 2] = f2bf(v.z); tile[r][cq * 4 + 3] = f2bf(v.w);
  }
  __syncthreads();
#pragma unroll
  for (int i = 0; i < 4; i++) {
    int c = i * 256 + t;
    int rn = c >> 4, cq = c & 15;
    ushort4 v;
    v.x = tile[cq * 4 + 0][rn];
    v.y = tile[cq * 4 + 1][rn];
    v.z = tile[cq * 4 + 2][rn];
    v.w = tile[cq * 4 + 3][rn];
    *(ushort4*)(Wt + (size_t)(n0 + rn) * K + k0 + cq * 4) = v;
  }
}

// ================= 256x256 GEMM for QKV: compiler-scheduled K-tile ==========
// Per iter: vmcnt(0); BAR; stage t+1 -> buf^1; 24 ds_reads + 64 MFMA with NO
// explicit waits between (compiler emits counted lgkmcnt -> reads overlap
// MFMA); trailing lgkmcnt(0) for WAR safety at next barrier.
__global__ __launch_bounds__(512, 1) void gemm8_qkv(
    const u16* __restrict__ A,
    const u16* __restrict__ B0, const u16* __restrict__ B1,
    const u16* __restrict__ B2,
    u16* __restrict__ Qo, u16* __restrict__ Ko, u16* __restrict__ Vt) {
  __shared__ __align__(16) u16 As[2][256 * 64];
  __shared__ __align__(16) u16 Bs[2][256 * 64];
  const int t = threadIdx.x;
  const int lane = t & 63;
  const int w = t >> 6;
  const int wr = w >> 2;
  const int wc = w & 3;
  const int g = lane >> 4;
  const int l15 = lane & 15;
  const int NT = KDIM / 64;  // 64

  const int bid = blockIdx.x;
  const int swz = (bid & 7) * 32 + (bid >> 3);
  const int mb = swz & 7;
  const int nb = swz >> 3;
  const int m0 = mb * 256;

  const u16* Bt; int nrow0;
  if (nb < 16)      { Bt = B0; nrow0 = nb * 256; }
  else if (nb < 24) { Bt = B1; nrow0 = (nb - 16) * 256; }
  else              { Bt = B2; nrow0 = (nb - 24) * 256; }

  auto stA = [&](int buf, int kt, int h) {
#pragma unroll
    for (int i = 0; i < 2; i++) {
      int c = i * 512 + t;
      int row = c >> 3, sp = c & 7;
      int col = (sp ^ (row & 7)) << 3;
      g2l16(A + (size_t)(m0 + h * 128 + row) * KDIM + kt + col,
            &As[buf][h * 8192 + c * 8]);
    }
  };
  auto stB = [&](int buf, int kt, int h) {
#pragma unroll
    for (int i = 0; i < 2; i++) {
      int c = i * 512 + t;
      int row = c >> 3, sp = c & 7;
      int col = (sp ^ (row & 7)) << 3;
      g2l16(Bt + (size_t)(nrow0 + h * 128 + row) * KDIM + kt + col,
            &Bs[buf][h * 8192 + c * 8]);
    }
  };

  f32x4 acc[8][4];
#pragma unroll
  for (int i = 0; i < 8; i++)
#pragma unroll
    for (int j = 0; j < 4; j++) acc[i][j] = (f32x4){0.f, 0.f, 0.f, 0.f};

  // prologue: stage tile 0
  stA(0, 0, 0); stA(0, 0, 1); stB(0, 0, 0); stB(0, 0, 1);

  for (int ti = 0; ti < NT; ++ti) {
    const int cur = ti & 1;
    const u16* Asc = As[cur];
    const u16* Bsc = Bs[cur];
    const int kt1 = (ti + 1) * 64;

    asm volatile("s_waitcnt vmcnt(0)" ::: "memory");  // tile t landed
    BAR();
    if (ti + 1 < NT) {
      stA(cur ^ 1, kt1, 0); stA(cur ^ 1, kt1, 1);
      stB(cur ^ 1, kt1, 0); stB(cur ^ 1, kt1, 1);
    }
    // fragments of tile t — no explicit waits; compiler interleaves with MFMA
    bf16x8 a0[2][4], a1[2][4], b0[2][2], b1[2][2];
#pragma unroll
    for (int kk = 0; kk < 2; kk++) {
#pragma unroll
      for (int mi = 0; mi < 4; mi++) {
        int r0 = wr * 128 + mi * 16 + l15;
        int s0 = (kk * 4 + g) ^ (r0 & 7);
        a0[kk][mi] = *(const bf16x8*)(Asc + r0 * 64 + s0 * 8);
      }
#pragma unroll
      for (int ni = 0; ni < 2; ni++) {
        int r0 = wc * 64 + ni * 16 + l15;
        int s0 = (kk * 4 + g) ^ (r0 & 7);
        b0[kk][ni] = *(const bf16x8*)(Bsc + r0 * 64 + s0 * 8);
      }
    }
#pragma unroll
    for (int kk = 0; kk < 2; kk++) {
#pragma unroll
      for (int mi = 0; mi < 4; mi++) {
        int r1 = wr * 128 + 64 + mi * 16 + l15;
        int s1 = (kk * 4 + g) ^ (r1 & 7);
        a1[kk][mi] = *(const bf16x8*)(Asc + r1 * 64 + s1 * 8);
      }
#pragma unroll
      for (int ni = 0; ni < 2; ni++) {
        int r1 = wc * 64 + (ni + 2) * 16 + l15;
        int s1 = (kk * 4 + g) ^ (r1 & 7);
        b1[kk][ni] = *(const bf16x8*)(Bsc + r1 * 64 + s1 * 8);
      }
    }
    __builtin_amdgcn_s_setprio(1);
#pragma unroll
    for (int mi = 0; mi < 4; mi++)
#pragma unroll
      for (int ni = 0; ni < 2; ni++)
#pragma unroll
        for (int kk = 0; kk < 2; kk++)
          acc[mi][ni] = __builtin_amdgcn_mfma_f32_16x16x32_bf16(
              a0[kk][mi], b0[kk][ni], acc[mi][ni], 0, 0, 0);
#pragma unroll
    for (int mi = 0; mi < 4; mi++)
#pragma unroll
      for (int ni = 0; ni < 2; ni++)
#pragma unroll
        for (int kk = 0; kk < 2; kk++)
          acc[mi + 4][ni] = __builtin_amdgcn_mfma_f32_16x16x32_bf16(
              a1[kk][mi], b0[kk][ni], acc[mi + 4][ni], 0, 0, 0);
#pragma unroll
    for (int mi = 0; mi < 4; mi++)
#pragma unroll
      for (int ni = 0; ni < 2; ni++)
#pragma unroll
        for (int kk = 0; kk < 2; kk++)
          acc[mi + 4][ni + 2] = __builtin_amdgcn_mfma_f32_16x16x32_bf16(
              a1[kk][mi], b1[kk][ni], acc[mi + 4][ni + 2], 0, 0, 0);
#pragma unroll
    for (int mi = 0; mi < 4; mi++)
#pragma unroll
      for (int ni = 0; ni < 2; ni++)
#pragma unroll
        for (int kk = 0; kk < 2; kk++)
          acc[mi][ni + 2] = __builtin_amdgcn_mfma_f32_16x16x32_bf16(
              a0[kk][mi], b1[kk][ni], acc[mi][ni + 2], 0, 0, 0);
    __builtin_amdgcn_s_setprio(0);
    asm volatile("s_waitcnt lgkmcnt(0)" ::: "memory");  // WAR safety (free)
  }

#pragma unroll
  for (int mi = 0; mi < 8; mi++) {
#pragma unroll
    for (int ni = 0; ni < 4; ni++) {
      int rowg = m0 + wr * 128 + mi * 16 + g * 4;
      int ncol = nb * 256 + wc * 64 + ni * 16 + l15;
      if (nb < 16) {
#pragma unroll
        for (int r = 0; r < 4; r++)
          Qo[(size_t)(rowg + r) * EMBED + ncol] = f2bf(acc[mi][ni][r]);
      } else if (nb < 24) {
        int nc = ncol - 4096;
#pragma unroll
        for (int r = 0; r < 4; r++)
          Ko[(size_t)(rowg + r) * KVW + nc] = f2bf(acc[mi][ni][r]);
      } else {
        int nc = ncol - 6144;  // kv_head*128 + d
        ushort4 v;
        v.x = f2bf(acc[mi][ni][0]); v.y = f2bf(acc[mi][ni][1]);
        v.z = f2bf(acc[mi][ni][2]); v.w = f2bf(acc[mi][ni][3]);
        *(ushort4*)(Vt + (size_t)nc * SEQ + rowg) = v;
      }
    }
  }
}

// ================= out-proj: BM=128 x BN=256, compiler-scheduled, f32 out ===
__global__ __launch_bounds__(512, 1) void gemm8_op(
    const u16* __restrict__ A, const u16* __restrict__ Bt,
    float* __restrict__ Cf) {
  __shared__ __align__(16) u16 As[2][128 * 64];
  __shared__ __align__(16) u16 Bs[2][256 * 64];
  const int t = threadIdx.x;
  const int lane = t & 63;
  const int w = t >> 6;
  const int wr = w >> 2;
  const int wc = w & 3;
  const int g = lane >> 4;
  const int l15 = lane & 15;
  const int NT = KDIM / 64;

  const int bid = blockIdx.x;
  const int swz = (bid & 7) * 32 + (bid >> 3);
  const int mb = swz & 15;
  const int nb = swz >> 4;
  const int m0 = mb * 128;
  const int nrow0 = nb * 256;

  auto stA = [&](int buf, int kt) {
#pragma unroll
    for (int i = 0; i < 2; i++) {
      int c = i * 512 + t;
      int row = c >> 3, sp = c & 7;
      int col = (sp ^ (row & 7)) << 3;
      g2l16(A + (size_t)(m0 + row) * KDIM + kt + col, &As[buf][c * 8]);
    }
  };
  auto stB = [&](int buf, int kt) {
#pragma unroll
    for (int i = 0; i < 4; i++) {
      int c = i * 512 + t;
      int row = c >> 3, sp = c & 7;
      int col = (sp ^ (row & 7)) << 3;
      g2l16(Bt + (size_t)(nrow0 + row) * KDIM + kt + col, &Bs[buf][c * 8]);
    }
  };

  f32x4 acc[4][4];
#pragma unroll
  for (int i = 0; i < 4; i++)
#pragma unroll
    for (int j = 0; j < 4; j++) acc[i][j] = (f32x4){0.f, 0.f, 0.f, 0.f};

  stA(0, 0); stB(0, 0);

  for (int ti = 0; ti < NT; ++ti) {
    const int cur = ti & 1;
    const u16* Asc = As[cur];
    const u16* Bsc = Bs[cur];
    const int kt1 = (ti + 1) * 64;

    asm volatile("s_waitcnt vmcnt(0)" ::: "memory");
    BAR();
    if (ti + 1 < NT) { stA(cur ^ 1, kt1); stB(cur ^ 1, kt1); }

    bf16x8 a[2][4], b0[2][2], b1[2][2];
#pragma unroll
    for (int kk = 0; kk < 2; kk++) {
#pragma unroll
      for (int mi = 0; mi < 4; mi++) {
        int r = wr * 64 + mi * 16 + l15;
        int sl = (kk * 4 + g) ^ (r & 7);
        a[kk][mi] = *(const bf16x8*)(Asc + r * 64 + sl * 8);
      }
#pragma unroll
      for (int ni = 0; ni < 2; ni++) {
        int r = wc * 64 + ni * 16 + l15;
        int sl = (kk * 4 + g) ^ (r & 7);
        b0[kk][ni] = *(const bf16x8*)(Bsc + r * 64 + sl * 8);
      }
#pragma unroll
      for (int ni = 0; ni < 2; ni++) {
        int r = wc * 64 + (ni + 2) * 16 + l15;
        int sl = (kk * 4 + g) ^ (r & 7);
        b1[kk][ni] = *(const bf16x8*)(Bsc + r * 64 + sl * 8);
      }
    }
    __builtin_amdgcn_s_setprio(1);
#pragma unroll
    for (int mi = 0; mi < 4; mi++)
#pragma unroll
      for (int ni = 0; ni < 2; ni++)
#pragma unroll
        for (int kk = 0; kk < 2; kk++)
          acc[mi][ni] = __builtin_amdgcn_mfma_f32_16x16x32_bf16(
              a[kk][mi], b0[kk][ni], acc[mi][ni], 0, 0, 0);
#pragma unroll
    for (int mi = 0; mi < 4; mi++)
#pragma unroll
      for (int ni = 0; ni < 2; ni++)
#pragma unroll
        for (int kk = 0; kk < 2; kk++)
          acc[mi][ni + 2] = __builtin_amdgcn_mfma_f32_16x16x32_bf16(
              a[kk][mi], b1[kk][ni], acc[mi][ni + 2], 0, 0, 0);
    __builtin_amdgcn_s_setprio(0);
    asm volatile("s_waitcnt lgkmcnt(0)" ::: "memory");
  }

#pragma unroll
  for (int mi = 0; mi < 4; mi++)
#pragma unroll
    for (int ni = 0; ni < 4; ni++) {
      int rowg = m0 + wr * 64 + mi * 16 + g * 4;
      int ncol = nb * 256 + wc * 64 + ni * 16 + l15;
#pragma unroll
      for (int r = 0; r < 4; r++)
        Cf[(size_t)(rowg + r) * 4096 + ncol] = acc[mi][ni][r];
    }
}

// ---------------- RoPE (in place) on Q [2048][4096] and K [2048][2048] ----
__global__ __launch_bounds__(256) void rope_kernel(
    u16* __restrict__ Q, u16* __restrict__ Kb,
    const float* __restrict__ freqs, const int* __restrict__ start_pos) {
  const int sp = start_pos[0];
  const float qscale = 0.08838834764831845f;  // 1/sqrt(128)
  const int total_q = SEQ * EMBED / 2;
  const int total_k = SEQ * KVW / 2;
  const int total = total_q + total_k;
  for (int idx = blockIdx.x * 256 + threadIdx.x; idx < total;
       idx += gridDim.x * 256) {
    u16* buf; int row, pi; bool isq = idx < total_q;
    if (isq) { row = idx >> 11; pi = idx & 2047; buf = Q + (size_t)row * EMBED; }
    else { int j = idx - total_q; row = j >> 10; pi = j & 1023; buf = Kb + (size_t)row * KVW; }
    int i = pi & 63;
    float2 cs = *(const float2*)(freqs + (size_t)(sp + row) * 128 + i * 2);
    float c = cs.x, s = cs.y;
    ushort2 tv = *(ushort2*)(buf + pi * 2);
    float t0 = bf2f(tv.x), t1 = bf2f(tv.y);
    float o0 = t0 * c - t1 * s;
    float o1 = t0 * s + t1 * c;
    if (isq) { o0 *= qscale; o1 *= qscale; }
    ushort2 o; o.x = f2bf(o0); o.y = f2bf(o1);
    *(ushort2*)(buf + pi * 2) = o;
  }
}

// ---------------- flash attention, causal, GQA (round-6 version) ----------
__global__ __launch_bounds__(256, 4) void attn_kernel(
    const u16* __restrict__ Q, const u16* __restrict__ Kb,
    const u16* __restrict__ Vt, u16* __restrict__ O) {
  __shared__ __align__(16) u16 KV[16384];   // K: [0,8192) 64x128, V: [8192,..) 128x64
  __shared__ u16 Ps[4][16 * 72];

  const int t = threadIdx.x;
  const int lane = t & 63;
  const int w = t >> 6;
  const int g = lane >> 4;
  const int l15 = lane & 15;
  const int bid = blockIdx.x;
  const int qb = 31 - (bid >> 5);
  const int h = bid & 31;
  const int hk = h >> 1;

  auto stageK = [&](int kv) {
#pragma unroll
    for (int i = 0; i < 4; i++) {
      int c = i * 256 + t;
      int row = c >> 4, spp = c & 15;
      int col = ((spp ^ (row & 7)) << 3);
      g2l16(Kb + (size_t)(kv * 64 + row) * KVW + hk * HD + col, &KV[c * 8]);
    }
  };
  auto stageV = [&](int kv) {
#pragma unroll
    for (int i = 0; i < 4; i++) {
      int c = i * 256 + t;
      int row = c >> 3, spp = c & 7;
      int col = ((spp ^ (row & 7)) << 3);
      g2l16(Vt + (size_t)(hk * HD + row) * SEQ + kv * 64 + col,
            &KV[8192 + c * 8]);
    }
  };

#pragma unroll
  for (int i = 0; i < 4; i++) {
    int c = i * 256 + t;
    int row = c >> 4, spp = c & 15;
    int col = ((spp ^ (row & 7)) << 3);
    g2l16(Q + (size_t)(qb * 64 + row) * EMBED + h * HD + col, &KV[c * 8]);
  }
  asm volatile("s_waitcnt vmcnt(0)" ::: "memory");
  __builtin_amdgcn_s_barrier();

  bf16x8 qf[4];
  {
    int r = w * 16 + l15;
#pragma unroll
    for (int kk = 0; kk < 4; kk++) {
      int ps = (kk * 4 + g) ^ (r & 7);
      qf[kk] = *(const bf16x8*)(&KV[r * 128 + ps * 8]);
    }
  }
  asm volatile("s_waitcnt lgkmcnt(0)" ::: "memory");
  __builtin_amdgcn_s_barrier();

  f32x4 oacc[8];
#pragma unroll
  for (int i = 0; i < 8; i++) oacc[i] = (f32x4){0.f, 0.f, 0.f, 0.f};
  float mrow = -1e30f, lrow = 0.f;
  const int qg = qb * 64 + w * 16 + l15;

  for (int kv = 0; kv <= qb; kv++) {
    stageK(kv); stageV(kv);
    asm volatile("s_waitcnt vmcnt(0)" ::: "memory");
    __builtin_amdgcn_s_barrier();

    f32x4 sfragT[4];
    __builtin_amdgcn_s_setprio(1);
#pragma unroll
    for (int ni = 0; ni < 4; ni++) {
      f32x4 s = (f32x4){0.f, 0.f, 0.f, 0.f};
      int r = ni * 16 + l15;
#pragma unroll
      for (int kk = 0; kk < 4; kk++) {
        int ps = (kk * 4 + g) ^ (r & 7);
        bf16x8 a = *(const bf16x8*)(&KV[r * 128 + ps * 8]);
        s = __builtin_amdgcn_mfma_f32_16x16x32_bf16(a, qf[kk], s, 0, 0, 0);
      }
      sfragT[ni] = s;
    }
    __builtin_amdgcn_s_setprio(0);

    if (kv == qb) {
#pragma unroll
      for (int ni = 0; ni < 4; ni++) {
        int colg = kv * 64 + ni * 16 + g * 4;
#pragma unroll
        for (int r = 0; r < 4; r++)
          if (colg + r > qg) sfragT[ni][r] = -1e30f;
      }
    }

    float m16 = sfragT[0][0];
#pragma unroll
    for (int ni = 0; ni < 4; ni++)
#pragma unroll
      for (int r = 0; r < 4; r++) m16 = fmaxf(m16, sfragT[ni][r]);
    m16 = fmaxf(m16, __shfl_xor(m16, 16));
    m16 = fmaxf(m16, __shfl_xor(m16, 32));
    float mnew = fmaxf(mrow, m16);
    float sc = __expf(mrow - mnew);
    mrow = mnew;

    float rsum = 0.f;
#pragma unroll
    for (int ni = 0; ni < 4; ni++) {
#pragma unroll
      for (int r = 0; r < 4; r++) {
        float p = __expf(sfragT[ni][r] - mrow);
        rsum += p;
        Ps[w][l15 * 72 + ni * 16 + g * 4 + r] = f2bf(p);
      }
    }
    rsum += __shfl_xor(rsum, 16);
    rsum += __shfl_xor(rsum, 32);
    lrow = lrow * sc + rsum;

    float scr[4];
#pragma unroll
    for (int r = 0; r < 4; r++) scr[r] = __shfl(sc, g * 4 + r, 64);
#pragma unroll
    for (int nf = 0; nf < 8; nf++)
#pragma unroll
      for (int r = 0; r < 4; r++) oacc[nf][r] *= scr[r];

    asm volatile("s_waitcnt lgkmcnt(0)" ::: "memory");

    bf16x8 pa[2];
#pragma unroll
    for (int kk = 0; kk < 2; kk++)
      pa[kk] = *(const bf16x8*)(&Ps[w][l15 * 72 + kk * 32 + g * 8]);
    __builtin_amdgcn_s_setprio(1);
#pragma unroll
    for (int nf = 0; nf < 8; nf++) {
      int r = nf * 16 + l15;
#pragma unroll
      for (int kk = 0; kk < 2; kk++) {
        int ps = (kk * 4 + g) ^ (r & 7);
        bf16x8 b = *(const bf16x8*)(&KV[8192 + r * 64 + ps * 8]);
        oacc[nf] = __builtin_amdgcn_mfma_f32_16x16x32_bf16(pa[kk], b, oacc[nf], 0, 0, 0);
      }
    }
    __builtin_amdgcn_s_setprio(0);
    __builtin_amdgcn_s_barrier();
  }

  float lr[4];
#pragma unroll
  for (int r = 0; r < 4; r++) lr[r] = __shfl(lrow, g * 4 + r, 64);
#pragma unroll
  for (int nf = 0; nf < 8; nf++) {
#pragma unroll
    for (int r = 0; r < 4; r++) {
      int rowg = qb * 64 + w * 16 + g * 4 + r;
      float v = oacc[nf][r] / lr[r];
      O[(size_t)rowg * EMBED + h * HD + nf * 16 + l15] = f2bf(v);
    }
  }
}

extern "C" void kernel_launch(void* const* d_in, const int* in_sizes, int n_in,
                              void* d_out, int out_size, void* d_ws, size_t ws_size,
                              hipStream_t stream) {
  const float* x  = (const float*)d_in[0];
  const float* fc = (const float*)d_in[1];
  const float* wq = (const float*)d_in[2];
  const float* wk = (const float*)d_in[3];
  const float* wv = (const float*)d_in[4];
  const float* wo = (const float*)d_in[5];
  const int* sp = (const int*)d_in[6];

  char* ws = (char*)d_ws;
  u16* wqT = (u16*)(ws);                      // bf16 [4096][4096]
  u16* wkT = (u16*)(ws + 33554432ull);        // bf16 [2048][4096]
  u16* wvT = (u16*)(ws + 50331648ull);        // bf16 [2048][4096]
  u16* woT = (u16*)(ws + 67108864ull);        // bf16 [4096][4096]
  u16* xb  = (u16*)(ws + 100663296ull);       // bf16 [2048][4096]
  u16* Qb  = (u16*)(ws + 117440512ull);       // bf16 [2048][4096]
  u16* Kb  = (u16*)(ws + 134217728ull);       // bf16 [2048][2048]
  u16* Vt  = (u16*)(ws + 142606336ull);       // bf16 [2048][2048]
  u16* Ob  = (u16*)(ws + 150994944ull);       // bf16 [2048][4096]

  convert_x<<<dim3(2048), 256, 0, stream>>>(x, xb, SEQ * EMBED / 4);
  transpose_cvt<<<dim3(64, 64), 256, 0, stream>>>(wq, wqT, 4096, 4096);
  transpose_cvt<<<dim3(32, 64), 256, 0, stream>>>(wk, wkT, 4096, 2048);
  transpose_cvt<<<dim3(32, 64), 256, 0, stream>>>(wv, wvT, 4096, 2048);
  transpose_cvt<<<dim3(64, 64), 256, 0, stream>>>(wo, woT, 4096, 4096);

  gemm8_qkv<<<dim3(256), 512, 0, stream>>>(xb, wqT, wkT, wvT, Qb, Kb, Vt);
  rope_kernel<<<dim3(2048), 256, 0, stream>>>(Qb, Kb, fc, sp);
  attn_kernel<<<dim3(1024), 256, 0, stream>>>(Qb, Kb, Vt, Ob);
  gemm8_op<<<dim3(256), 512, 0, stream>>>(Ob, woT, (float*)d_out);
}

// Round 10
// 366.516 us; speedup vs baseline: 2.1742x; 1.0390x over previous
//
#include <hip/hip_runtime.h>
#include <stdint.h>

typedef unsigned short u16;
typedef __bf16 bf16x8 __attribute__((ext_vector_type(8)));
typedef float f32x4 __attribute__((ext_vector_type(4)));

#define SEQ   2048
#define EMBED 4096
#define KDIM  4096
#define NH    32
#define NKV   16
#define HD    128
#define KVW   2048   // N_KV_HEADS * HD

__device__ __forceinline__ float bf2f(u16 u) {
  union { uint32_t u; float f; } v; v.u = ((uint32_t)u) << 16; return v.f;
}
__device__ __forceinline__ u16 f2bf(float f) {
  union { float f; uint32_t u; } v; v.f = f;
  return (u16)((v.u + 0x7FFFu + ((v.u >> 16) & 1u)) >> 16);
}
__device__ __forceinline__ void g2l16(const u16* g, u16* l) {
  __builtin_amdgcn_global_load_lds(
      (const __attribute__((address_space(1))) uint32_t*)g,
      (__attribute__((address_space(3))) uint32_t*)l, 16, 0, 0);
}

// ---------------- prep: x f32->bf16 + all 4 weight transpose+convert --------
// blocks [0,2048): convert x; then wq(4096) wk(2048) wv(2048) wo(4096) tiles.
__global__ __launch_bounds__(256) void prep_kernel(
    const float* __restrict__ X, u16* __restrict__ Xb,
    const float* __restrict__ wq, u16* __restrict__ wqT,
    const float* __restrict__ wk, u16* __restrict__ wkT,
    const float* __restrict__ wv, u16* __restrict__ wvT,
    const float* __restrict__ wo, u16* __restrict__ woT) {
  __shared__ u16 tile[64][68];
  int b = blockIdx.x;
  const int t = threadIdx.x;
  if (b < 2048) {
    const int nquad = SEQ * EMBED / 4;
    for (int i = b * 256 + t; i < nquad; i += 2048 * 256) {
      float4 v = *(const float4*)(X + (size_t)i * 4);
      ushort4 o;
      o.x = f2bf(v.x); o.y = f2bf(v.y); o.z = f2bf(v.z); o.w = f2bf(v.w);
      *(ushort4*)(Xb + (size_t)i * 4) = o;
    }
    return;
  }
  b -= 2048;
  const float* W; u16* Wt; int N, local;
  if (b < 4096)      { W = wq; Wt = wqT; N = 4096; local = b; }
  else if (b < 6144) { W = wk; Wt = wkT; N = 2048; local = b - 4096; }
  else if (b < 8192) { W = wv; Wt = wvT; N = 2048; local = b - 6144; }
  else               { W = wo; Wt = woT; N = 4096; local = b - 8192; }
  const int nx = N >> 6;
  const int n0 = (local % nx) * 64, k0 = (local / nx) * 64;
#pragma unroll
  for (int i = 0; i < 4; i++) {
    int c = i * 256 + t;
    int r = c >> 4, cq = c & 15;
    float4 v = *(const float4*)(W + (size_t)(k0 + r) * N + n0 + cq * 4);
    tile[r][cq * 4 + 0] = f2bf(v.x); tile[r][cq * 4 + 1] = f2bf(v.y);
    tile[r][cq * 4 + 2] = f2bf(v.z); tile[r][cq * 4 + 3] = f2bf(v.w);
  }
  __syncthreads();
#pragma unroll
  for (int i = 0; i < 4; i++) {
    int c = i * 256 + t;
    int rn = c >> 4, cq = c & 15;
    ushort4 v;
    v.x = tile[cq * 4 + 0][rn];
    v.y = tile[cq * 4 + 1][rn];
    v.z = tile[cq * 4 + 2][rn];
    v.w = tile[cq * 4 + 3][rn];
    *(ushort4*)(Wt + (size_t)(n0 + rn) * KDIM + k0 + cq * 4) = v;
  }
}

// ================= 256x256 GEMM for QKV (round-6 schedule) =================
// Depth-2 prefetch; 4 phases/K-tile; fused RoPE in epilogue (Q scaled).
__global__ __launch_bounds__(512, 2) void gemm8_qkv(
    const u16* __restrict__ A,
    const u16* __restrict__ B0, const u16* __restrict__ B1,
    const u16* __restrict__ B2,
    u16* __restrict__ Qo, u16* __restrict__ Ko, u16* __restrict__ Vt,
    const float* __restrict__ freqs, const int* __restrict__ start_pos) {
  __shared__ __align__(16) u16 As[2][256 * 64];
  __shared__ __align__(16) u16 Bs[2][256 * 64];
  const int t = threadIdx.x;
  const int lane = t & 63;
  const int w = t >> 6;
  const int wr = w >> 2;
  const int wc = w & 3;
  const int g = lane >> 4;
  const int l15 = lane & 15;

  const int bid = blockIdx.x;
  const int swz = (bid & 7) * 32 + (bid >> 3);
  const int mb = swz & 7;
  const int nb = swz >> 3;
  const int m0 = mb * 256;

  const u16* Bt; int nrow0;
  if (nb < 16)      { Bt = B0; nrow0 = nb * 256; }
  else if (nb < 24) { Bt = B1; nrow0 = (nb - 16) * 256; }
  else              { Bt = B2; nrow0 = (nb - 24) * 256; }

  auto stageA = [&](int buf, int kt, int h) {
#pragma unroll
    for (int i = 0; i < 2; i++) {
      int c = i * 512 + t;
      int row = c >> 3, sp = c & 7;
      int col = (sp ^ (row & 7)) << 3;
      g2l16(A + (size_t)(m0 + h * 128 + row) * KDIM + kt + col,
            &As[buf][h * 8192 + c * 8]);
    }
  };
  auto stageB = [&](int buf, int kt, int h) {
#pragma unroll
    for (int i = 0; i < 2; i++) {
      int c = i * 512 + t;
      int row = c >> 3, sp = c & 7;
      int col = (sp ^ (row & 7)) << 3;
      g2l16(Bt + (size_t)(nrow0 + h * 128 + row) * KDIM + kt + col,
            &Bs[buf][h * 8192 + c * 8]);
    }
  };

  f32x4 acc[8][4];
#pragma unroll
  for (int i = 0; i < 8; i++)
#pragma unroll
    for (int j = 0; j < 4; j++) acc[i][j] = (f32x4){0.f, 0.f, 0.f, 0.f};

  // prologue: tiles 0 and 1 fully staged (16 loads); wait tile 0 (8 left)
  stageA(0, 0, 0); stageA(0, 0, 1);
  stageB(0, 0, 0); stageB(0, 0, 1);
  stageA(1, 64, 0); stageA(1, 64, 1);
  stageB(1, 64, 0); stageB(1, 64, 1);
  asm volatile("s_waitcnt vmcnt(8)" ::: "memory");
  __builtin_amdgcn_s_barrier();

  const int NT = KDIM / 64;  // 64
  for (int ti = 0; ti < NT; ++ti) {
    const int cur = ti & 1;
    const u16* Asc = As[cur];
    const u16* Bsc = Bs[cur];
    const int ktn2 = (ti + 2) * 64;
    bf16x8 a0[2][4], a1[2][4], b0[2][2], b1[2][2];

    // ---- phase 0: read a0+b0 ; MFMA Q00 ----
#pragma unroll
    for (int kk = 0; kk < 2; kk++)
#pragma unroll
      for (int mi = 0; mi < 4; mi++) {
        int r = wr * 128 + mi * 16 + l15;
        int slot = (kk * 4 + g) ^ (r & 7);
        a0[kk][mi] = *(const bf16x8*)(Asc + r * 64 + slot * 8);
      }
#pragma unroll
    for (int kk = 0; kk < 2; kk++)
#pragma unroll
      for (int ni = 0; ni < 2; ni++) {
        int r = wc * 64 + ni * 16 + l15;
        int slot = (kk * 4 + g) ^ (r & 7);
        b0[kk][ni] = *(const bf16x8*)(Bsc + r * 64 + slot * 8);
      }
    __builtin_amdgcn_s_barrier();
    asm volatile("s_waitcnt lgkmcnt(0)" ::: "memory");
    __builtin_amdgcn_sched_barrier(0);
    __builtin_amdgcn_s_setprio(1);
#pragma unroll
    for (int mi = 0; mi < 4; mi++)
#pragma unroll
      for (int ni = 0; ni < 2; ni++)
#pragma unroll
        for (int kk = 0; kk < 2; kk++)
          acc[mi][ni] = __builtin_amdgcn_mfma_f32_16x16x32_bf16(
              a0[kk][mi], b0[kk][ni], acc[mi][ni], 0, 0, 0);
    __builtin_amdgcn_s_setprio(0);
    __builtin_amdgcn_s_barrier();

    // ---- phase 1: read a1 ; MFMA Q10 ----
#pragma unroll
    for (int kk = 0; kk < 2; kk++)
#pragma unroll
      for (int mi = 0; mi < 4; mi++) {
        int r = wr * 128 + 64 + mi * 16 + l15;
        int slot = (kk * 4 + g) ^ (r & 7);
        a1[kk][mi] = *(const bf16x8*)(Asc + r * 64 + slot * 8);
      }
    __builtin_amdgcn_s_barrier();
    asm volatile("s_waitcnt lgkmcnt(0)" ::: "memory");
    __builtin_amdgcn_sched_barrier(0);
    __builtin_amdgcn_s_setprio(1);
#pragma unroll
    for (int mi = 0; mi < 4; mi++)
#pragma unroll
      for (int ni = 0; ni < 2; ni++)
#pragma unroll
        for (int kk = 0; kk < 2; kk++)
          acc[mi + 4][ni] = __builtin_amdgcn_mfma_f32_16x16x32_bf16(
              a1[kk][mi], b0[kk][ni], acc[mi + 4][ni], 0, 0, 0);
    __builtin_amdgcn_s_setprio(0);
    __builtin_amdgcn_s_barrier();

    // ---- phase 2: read b1 ; stage A(t+2) ; MFMA Q11 ----
#pragma unroll
    for (int kk = 0; kk < 2; kk++)
#pragma unroll
      for (int ni = 0; ni < 2; ni++) {
        int r = wc * 64 + (ni + 2) * 16 + l15;
        int slot = (kk * 4 + g) ^ (r & 7);
        b1[kk][ni] = *(const bf16x8*)(Bsc + r * 64 + slot * 8);
      }
    if (ti + 2 < NT) { stageA(cur, ktn2, 0); stageA(cur, ktn2, 1); }
    __builtin_amdgcn_s_barrier();
    asm volatile("s_waitcnt lgkmcnt(0)" ::: "memory");
    __builtin_amdgcn_sched_barrier(0);
    __builtin_amdgcn_s_setprio(1);
#pragma unroll
    for (int mi = 0; mi < 4; mi++)
#pragma unroll
      for (int ni = 0; ni < 2; ni++)
#pragma unroll
        for (int kk = 0; kk < 2; kk++)
          acc[mi + 4][ni + 2] = __builtin_amdgcn_mfma_f32_16x16x32_bf16(
              a1[kk][mi], b1[kk][ni], acc[mi + 4][ni + 2], 0, 0, 0);
    __builtin_amdgcn_s_setprio(0);
    __builtin_amdgcn_s_barrier();

    // ---- phase 3: stage B(t+2) ; MFMA Q01 ; vmcnt(8) ----
    if (ti + 2 < NT) { stageB(cur, ktn2, 0); stageB(cur, ktn2, 1); }
    __builtin_amdgcn_s_barrier();
    __builtin_amdgcn_s_setprio(1);
#pragma unroll
    for (int mi = 0; mi < 4; mi++)
#pragma unroll
      for (int ni = 0; ni < 2; ni++)
#pragma unroll
        for (int kk = 0; kk < 2; kk++)
          acc[mi][ni + 2] = __builtin_amdgcn_mfma_f32_16x16x32_bf16(
              a0[kk][mi], b1[kk][ni], acc[mi][ni + 2], 0, 0, 0);
    __builtin_amdgcn_s_setprio(0);
    if (ti + 2 < NT)      asm volatile("s_waitcnt vmcnt(8)" ::: "memory");
    else if (ti + 1 < NT) asm volatile("s_waitcnt vmcnt(0)" ::: "memory");
    __builtin_amdgcn_s_barrier();
  }

  // epilogue with fused RoPE for Q (scaled) and K regions
  const int sp = start_pos[0];
  const float qscale = 0.08838834764831845f;  // 1/sqrt(128)
#pragma unroll
  for (int mi = 0; mi < 8; mi++) {
#pragma unroll
    for (int ni = 0; ni < 4; ni++) {
      int rowg = m0 + wr * 128 + mi * 16 + g * 4;
      int ncol = nb * 256 + wc * 64 + ni * 16 + l15;
      if (nb < 24) {
        int d = ncol & 127;
        int i2 = d >> 1;
        bool odd = d & 1;
        float scale = (nb < 16) ? qscale : 1.f;
#pragma unroll
        for (int r = 0; r < 4; r++) {
          float2 cs = *(const float2*)(freqs + (size_t)(sp + rowg + r) * 128 + i2 * 2);
          float v = acc[mi][ni][r] * scale;
          float p = __shfl_xor(v, 1);  // pair partner (ncol^1 <-> lane^1)
          float o = cs.x * v + cs.y * (odd ? p : -p);
          if (nb < 16)
            Qo[(size_t)(rowg + r) * EMBED + ncol] = f2bf(o);
          else
            Ko[(size_t)(rowg + r) * KVW + (ncol - 4096)] = f2bf(o);
        }
      } else {
        int nc = ncol - 6144;  // kv_head*128 + d
        ushort4 v;
        v.x = f2bf(acc[mi][ni][0]); v.y = f2bf(acc[mi][ni][1]);
        v.z = f2bf(acc[mi][ni][2]); v.w = f2bf(acc[mi][ni][3]);
        *(ushort4*)(Vt + (size_t)nc * SEQ + rowg) = v;
      }
    }
  }
}

// ================= out-proj: BM=128 x BN=256, 2-phase/K-tile, f32 out ======
// (round-6 version, unchanged — known good)
__global__ __launch_bounds__(512, 2) void gemm8_op(
    const u16* __restrict__ A, const u16* __restrict__ Bt,
    float* __restrict__ Cf) {
  __shared__ __align__(16) u16 As[2][128 * 64];
  __shared__ __align__(16) u16 Bs[2][256 * 64];
  const int t = threadIdx.x;
  const int lane = t & 63;
  const int w = t >> 6;
  const int wr = w >> 2;
  const int wc = w & 3;
  const int g = lane >> 4;
  const int l15 = lane & 15;

  const int bid = blockIdx.x;
  const int swz = (bid & 7) * 32 + (bid >> 3);
  const int mb = swz & 15;
  const int nb = swz >> 4;
  const int m0 = mb * 128;
  const int nrow0 = nb * 256;

  auto stageA = [&](int buf, int kt) {
#pragma unroll
    for (int i = 0; i < 2; i++) {
      int c = i * 512 + t;
      int row = c >> 3, sp = c & 7;
      int col = (sp ^ (row & 7)) << 3;
      g2l16(A + (size_t)(m0 + row) * KDIM + kt + col, &As[buf][c * 8]);
    }
  };
  auto stageB = [&](int buf, int kt) {
#pragma unroll
    for (int i = 0; i < 4; i++) {
      int c = i * 512 + t;
      int row = c >> 3, sp = c & 7;
      int col = (sp ^ (row & 7)) << 3;
      g2l16(Bt + (size_t)(nrow0 + row) * KDIM + kt + col, &Bs[buf][c * 8]);
    }
  };

  f32x4 acc[4][4];
#pragma unroll
  for (int i = 0; i < 4; i++)
#pragma unroll
    for (int j = 0; j < 4; j++) acc[i][j] = (f32x4){0.f, 0.f, 0.f, 0.f};

  stageA(0, 0); stageB(0, 0);
  stageA(1, 64); stageB(1, 64);
  asm volatile("s_waitcnt vmcnt(6)" ::: "memory");
  __builtin_amdgcn_s_barrier();

  const int NT = KDIM / 64;
  for (int ti = 0; ti < NT; ++ti) {
    const int cur = ti & 1;
    const u16* Asc = As[cur];
    const u16* Bsc = Bs[cur];
    const int ktn2 = (ti + 2) * 64;
    bf16x8 a[2][4], b0[2][2], b1[2][2];

#pragma unroll
    for (int kk = 0; kk < 2; kk++)
#pragma unroll
      for (int mi = 0; mi < 4; mi++) {
        int r = wr * 64 + mi * 16 + l15;
        int slot = (kk * 4 + g) ^ (r & 7);
        a[kk][mi] = *(const bf16x8*)(Asc + r * 64 + slot * 8);
      }
#pragma unroll
    for (int kk = 0; kk < 2; kk++)
#pragma unroll
      for (int ni = 0; ni < 2; ni++) {
        int r = wc * 64 + ni * 16 + l15;
        int slot = (kk * 4 + g) ^ (r & 7);
        b0[kk][ni] = *(const bf16x8*)(Bsc + r * 64 + slot * 8);
      }
#pragma unroll
    for (int kk = 0; kk < 2; kk++)
#pragma unroll
      for (int ni = 0; ni < 2; ni++) {
        int r = wc * 64 + (ni + 2) * 16 + l15;
        int slot = (kk * 4 + g) ^ (r & 7);
        b1[kk][ni] = *(const bf16x8*)(Bsc + r * 64 + slot * 8);
      }
    __builtin_amdgcn_s_barrier();
    asm volatile("s_waitcnt lgkmcnt(0)" ::: "memory");
    __builtin_amdgcn_sched_barrier(0);
    __builtin_amdgcn_s_setprio(1);
#pragma unroll
    for (int mi = 0; mi < 4; mi++)
#pragma unroll
      for (int ni = 0; ni < 2; ni++)
#pragma unroll
        for (int kk = 0; kk < 2; kk++)
          acc[mi][ni] = __builtin_amdgcn_mfma_f32_16x16x32_bf16(
              a[kk][mi], b0[kk][ni], acc[mi][ni], 0, 0, 0);
    __builtin_amdgcn_s_setprio(0);
    __builtin_amdgcn_s_barrier();

    if (ti + 2 < NT) { stageA(cur, ktn2); stageB(cur, ktn2); }
    __builtin_amdgcn_s_barrier();
    __builtin_amdgcn_s_setprio(1);
#pragma unroll
    for (int mi = 0; mi < 4; mi++)
#pragma unroll
      for (int ni = 0; ni < 2; ni++)
#pragma unroll
        for (int kk = 0; kk < 2; kk++)
          acc[mi][ni + 2] = __builtin_amdgcn_mfma_f32_16x16x32_bf16(
              a[kk][mi], b1[kk][ni], acc[mi][ni + 2], 0, 0, 0);
    __builtin_amdgcn_s_setprio(0);
    if (ti + 2 < NT)      asm volatile("s_waitcnt vmcnt(6)" ::: "memory");
    else if (ti + 1 < NT) asm volatile("s_waitcnt vmcnt(0)" ::: "memory");
    __builtin_amdgcn_s_barrier();
  }

#pragma unroll
  for (int mi = 0; mi < 4; mi++)
#pragma unroll
    for (int ni = 0; ni < 4; ni++) {
      int rowg = m0 + wr * 64 + mi * 16 + g * 4;
      int ncol = nb * 256 + wc * 64 + ni * 16 + l15;
#pragma unroll
      for (int r = 0; r < 4; r++)
        Cf[(size_t)(rowg + r) * 4096 + ncol] = acc[mi][ni][r];
    }
}

// ---------------- flash attention, causal, GQA (round-6 version) ----------
__global__ __launch_bounds__(256, 4) void attn_kernel(
    const u16* __restrict__ Q, const u16* __restrict__ Kb,
    const u16* __restrict__ Vt, u16* __restrict__ O) {
  __shared__ __align__(16) u16 KV[16384];   // K: [0,8192) 64x128, V: [8192,..) 128x64
  __shared__ u16 Ps[4][16 * 72];

  const int t = threadIdx.x;
  const int lane = t & 63;
  const int w = t >> 6;
  const int g = lane >> 4;
  const int l15 = lane & 15;
  const int bid = blockIdx.x;
  const int qb = 31 - (bid >> 5);
  const int h = bid & 31;
  const int hk = h >> 1;

  auto stageK = [&](int kv) {
#pragma unroll
    for (int i = 0; i < 4; i++) {
      int c = i * 256 + t;
      int row = c >> 4, spp = c & 15;
      int col = ((spp ^ (row & 7)) << 3);
      g2l16(Kb + (size_t)(kv * 64 + row) * KVW + hk * HD + col, &KV[c * 8]);
    }
  };
  auto stageV = [&](int kv) {
#pragma unroll
    for (int i = 0; i < 4; i++) {
      int c = i * 256 + t;
      int row = c >> 3, spp = c & 7;
      int col = ((spp ^ (row & 7)) << 3);
      g2l16(Vt + (size_t)(hk * HD + row) * SEQ + kv * 64 + col,
            &KV[8192 + c * 8]);
    }
  };

#pragma unroll
  for (int i = 0; i < 4; i++) {
    int c = i * 256 + t;
    int row = c >> 4, spp = c & 15;
    int col = ((spp ^ (row & 7)) << 3);
    g2l16(Q + (size_t)(qb * 64 + row) * EMBED + h * HD + col, &KV[c * 8]);
  }
  asm volatile("s_waitcnt vmcnt(0)" ::: "memory");
  __builtin_amdgcn_s_barrier();

  bf16x8 qf[4];
  {
    int r = w * 16 + l15;
#pragma unroll
    for (int kk = 0; kk < 4; kk++) {
      int ps = (kk * 4 + g) ^ (r & 7);
      qf[kk] = *(const bf16x8*)(&KV[r * 128 + ps * 8]);
    }
  }
  asm volatile("s_waitcnt lgkmcnt(0)" ::: "memory");
  __builtin_amdgcn_s_barrier();

  f32x4 oacc[8];
#pragma unroll
  for (int i = 0; i < 8; i++) oacc[i] = (f32x4){0.f, 0.f, 0.f, 0.f};
  float mrow = -1e30f, lrow = 0.f;
  const int qg = qb * 64 + w * 16 + l15;

  for (int kv = 0; kv <= qb; kv++) {
    stageK(kv); stageV(kv);
    asm volatile("s_waitcnt vmcnt(0)" ::: "memory");
    __builtin_amdgcn_s_barrier();

    f32x4 sfragT[4];
    __builtin_amdgcn_s_setprio(1);
#pragma unroll
    for (int ni = 0; ni < 4; ni++) {
      f32x4 s = (f32x4){0.f, 0.f, 0.f, 0.f};
      int r = ni * 16 + l15;
#pragma unroll
      for (int kk = 0; kk < 4; kk++) {
        int ps = (kk * 4 + g) ^ (r & 7);
        bf16x8 a = *(const bf16x8*)(&KV[r * 128 + ps * 8]);
        s = __builtin_amdgcn_mfma_f32_16x16x32_bf16(a, qf[kk], s, 0, 0, 0);
      }
      sfragT[ni] = s;
    }
    __builtin_amdgcn_s_setprio(0);

    if (kv == qb) {
#pragma unroll
      for (int ni = 0; ni < 4; ni++) {
        int colg = kv * 64 + ni * 16 + g * 4;
#pragma unroll
        for (int r = 0; r < 4; r++)
          if (colg + r > qg) sfragT[ni][r] = -1e30f;
      }
    }

    float m16 = sfragT[0][0];
#pragma unroll
    for (int ni = 0; ni < 4; ni++)
#pragma unroll
      for (int r = 0; r < 4; r++) m16 = fmaxf(m16, sfragT[ni][r]);
    m16 = fmaxf(m16, __shfl_xor(m16, 16));
    m16 = fmaxf(m16, __shfl_xor(m16, 32));
    float mnew = fmaxf(mrow, m16);
    float sc = __expf(mrow - mnew);
    mrow = mnew;

    float rsum = 0.f;
#pragma unroll
    for (int ni = 0; ni < 4; ni++) {
#pragma unroll
      for (int r = 0; r < 4; r++) {
        float p = __expf(sfragT[ni][r] - mrow);
        rsum += p;
        Ps[w][l15 * 72 + ni * 16 + g * 4 + r] = f2bf(p);
      }
    }
    rsum += __shfl_xor(rsum, 16);
    rsum += __shfl_xor(rsum, 32);
    lrow = lrow * sc + rsum;

    float scr[4];
#pragma unroll
    for (int r = 0; r < 4; r++) scr[r] = __shfl(sc, g * 4 + r, 64);
#pragma unroll
    for (int nf = 0; nf < 8; nf++)
#pragma unroll
      for (int r = 0; r < 4; r++) oacc[nf][r] *= scr[r];

    asm volatile("s_waitcnt lgkmcnt(0)" ::: "memory");

    bf16x8 pa[2];
#pragma unroll
    for (int kk = 0; kk < 2; kk++)
      pa[kk] = *(const bf16x8*)(&Ps[w][l15 * 72 + kk * 32 + g * 8]);
    __builtin_amdgcn_s_setprio(1);
#pragma unroll
    for (int nf = 0; nf < 8; nf++) {
      int r = nf * 16 + l15;
#pragma unroll
      for (int kk = 0; kk < 2; kk++) {
        int ps = (kk * 4 + g) ^ (r & 7);
        bf16x8 b = *(const bf16x8*)(&KV[8192 + r * 64 + ps * 8]);
        oacc[nf] = __builtin_amdgcn_mfma_f32_16x16x32_bf16(pa[kk], b, oacc[nf], 0, 0, 0);
      }
    }
    __builtin_amdgcn_s_setprio(0);
    __builtin_amdgcn_s_barrier();
  }

  float lr[4];
#pragma unroll
  for (int r = 0; r < 4; r++) lr[r] = __shfl(lrow, g * 4 + r, 64);
#pragma unroll
  for (int nf = 0; nf < 8; nf++) {
#pragma unroll
    for (int r = 0; r < 4; r++) {
      int rowg = qb * 64 + w * 16 + g * 4 + r;
      float v = oacc[nf][r] / lr[r];
      O[(size_t)rowg * EMBED + h * HD + nf * 16 + l15] = f2bf(v);
    }
  }
}

extern "C" void kernel_launch(void* const* d_in, const int* in_sizes, int n_in,
                              void* d_out, int out_size, void* d_ws, size_t ws_size,
                              hipStream_t stream) {
  const float* x  = (const float*)d_in[0];
  const float* fc = (const float*)d_in[1];
  const float* wq = (const float*)d_in[2];
  const float* wk = (const float*)d_in[3];
  const float* wv = (const float*)d_in[4];
  const float* wo = (const float*)d_in[5];
  const int* sp = (const int*)d_in[6];

  char* ws = (char*)d_ws;
  u16* wqT = (u16*)(ws);                      // bf16 [4096][4096]
  u16* wkT = (u16*)(ws + 33554432ull);        // bf16 [2048][4096]
  u16* wvT = (u16*)(ws + 50331648ull);        // bf16 [2048][4096]
  u16* woT = (u16*)(ws + 67108864ull);        // bf16 [4096][4096]
  u16* xb  = (u16*)(ws + 100663296ull);       // bf16 [2048][4096]
  u16* Qb  = (u16*)(ws + 117440512ull);       // bf16 [2048][4096]
  u16* Kb  = (u16*)(ws + 134217728ull);       // bf16 [2048][2048]
  u16* Vt  = (u16*)(ws + 142606336ull);       // bf16 [2048][2048]
  u16* Ob  = (u16*)(ws + 150994944ull);       // bf16 [2048][4096]

  prep_kernel<<<dim3(14336), 256, 0, stream>>>(x, xb, wq, wqT, wk, wkT,
                                               wv, wvT, wo, woT);
  gemm8_qkv<<<dim3(256), 512, 0, stream>>>(xb, wqT, wkT, wvT, Qb, Kb, Vt,
                                           fc, sp);
  attn_kernel<<<dim3(1024), 256, 0, stream>>>(Qb, Kb, Vt, Ob);
  gemm8_op<<<dim3(256), 512, 0, stream>>>(Ob, woT, (float*)d_out);
}

// Round 12
// 347.801 us; speedup vs baseline: 2.2912x; 1.0538x over previous
//
#include <hip/hip_runtime.h>
#include <stdint.h>

typedef unsigned short u16;
typedef __bf16 bf16x8 __attribute__((ext_vector_type(8)));
typedef float f32x4 __attribute__((ext_vector_type(4)));

#define SEQ   2048
#define EMBED 4096
#define KDIM  4096
#define NH    32
#define NKV   16
#define HD    128
#define KVW   2048   // N_KV_HEADS * HD

__device__ __forceinline__ float bf2f(u16 u) {
  union { uint32_t u; float f; } v; v.u = ((uint32_t)u) << 16; return v.f;
}
__device__ __forceinline__ u16 f2bf(float f) {
  union { float f; uint32_t u; } v; v.f = f;
  return (u16)((v.u + 0x7FFFu + ((v.u >> 16) & 1u)) >> 16);
}
__device__ __forceinline__ void g2l16(const u16* g, u16* l) {
  __builtin_amdgcn_global_load_lds(
      (const __attribute__((address_space(1))) uint32_t*)g,
      (__attribute__((address_space(3))) uint32_t*)l, 16, 0, 0);
}

// ---------------- prep: x f32->bf16 + all 4 weight transpose+convert --------
__global__ __launch_bounds__(256) void prep_kernel(
    const float* __restrict__ X, u16* __restrict__ Xb,
    const float* __restrict__ wq, u16* __restrict__ wqT,
    const float* __restrict__ wk, u16* __restrict__ wkT,
    const float* __restrict__ wv, u16* __restrict__ wvT,
    const float* __restrict__ wo, u16* __restrict__ woT) {
  __shared__ u16 tile[64][68];
  int b = blockIdx.x;
  const int t = threadIdx.x;
  if (b < 2048) {
    const int nquad = SEQ * EMBED / 4;
    for (int i = b * 256 + t; i < nquad; i += 2048 * 256) {
      float4 v = *(const float4*)(X + (size_t)i * 4);
      ushort4 o;
      o.x = f2bf(v.x); o.y = f2bf(v.y); o.z = f2bf(v.z); o.w = f2bf(v.w);
      *(ushort4*)(Xb + (size_t)i * 4) = o;
    }
    return;
  }
  b -= 2048;
  const float* W; u16* Wt; int N, local;
  if (b < 4096)      { W = wq; Wt = wqT; N = 4096; local = b; }
  else if (b < 6144) { W = wk; Wt = wkT; N = 2048; local = b - 4096; }
  else if (b < 8192) { W = wv; Wt = wvT; N = 2048; local = b - 6144; }
  else               { W = wo; Wt = woT; N = 4096; local = b - 8192; }
  const int nx = N >> 6;
  const int n0 = (local % nx) * 64, k0 = (local / nx) * 64;
#pragma unroll
  for (int i = 0; i < 4; i++) {
    int c = i * 256 + t;
    int r = c >> 4, cq = c & 15;
    float4 v = *(const float4*)(W + (size_t)(k0 + r) * N + n0 + cq * 4);
    tile[r][cq * 4 + 0] = f2bf(v.x); tile[r][cq * 4 + 1] = f2bf(v.y);
    tile[r][cq * 4 + 2] = f2bf(v.z); tile[r][cq * 4 + 3] = f2bf(v.w);
  }
  __syncthreads();
#pragma unroll
  for (int i = 0; i < 4; i++) {
    int c = i * 256 + t;
    int rn = c >> 4, cq = c & 15;
    ushort4 v;
    v.x = tile[cq * 4 + 0][rn];
    v.y = tile[cq * 4 + 1][rn];
    v.z = tile[cq * 4 + 2][rn];
    v.w = tile[cq * 4 + 3][rn];
    *(ushort4*)(Wt + (size_t)(n0 + rn) * KDIM + k0 + cq * 4) = v;
  }
}

// ================= 256x256 GEMM for QKV (round-6 schedule, plain epilogue) ==
__global__ __launch_bounds__(512, 2) void gemm8_qkv(
    const u16* __restrict__ A,
    const u16* __restrict__ B0, const u16* __restrict__ B1,
    const u16* __restrict__ B2,
    u16* __restrict__ Qo, u16* __restrict__ Ko, u16* __restrict__ Vt) {
  __shared__ __align__(16) u16 As[2][256 * 64];
  __shared__ __align__(16) u16 Bs[2][256 * 64];
  const int t = threadIdx.x;
  const int lane = t & 63;
  const int w = t >> 6;
  const int wr = w >> 2;
  const int wc = w & 3;
  const int g = lane >> 4;
  const int l15 = lane & 15;

  const int bid = blockIdx.x;
  const int swz = (bid & 7) * 32 + (bid >> 3);
  const int mb = swz & 7;
  const int nb = swz >> 3;
  const int m0 = mb * 256;

  const u16* Bt; int nrow0;
  if (nb < 16)      { Bt = B0; nrow0 = nb * 256; }
  else if (nb < 24) { Bt = B1; nrow0 = (nb - 16) * 256; }
  else              { Bt = B2; nrow0 = (nb - 24) * 256; }

  auto stageA = [&](int buf, int kt, int h) {
#pragma unroll
    for (int i = 0; i < 2; i++) {
      int c = i * 512 + t;
      int row = c >> 3, sp = c & 7;
      int col = (sp ^ (row & 7)) << 3;
      g2l16(A + (size_t)(m0 + h * 128 + row) * KDIM + kt + col,
            &As[buf][h * 8192 + c * 8]);
    }
  };
  auto stageB = [&](int buf, int kt, int h) {
#pragma unroll
    for (int i = 0; i < 2; i++) {
      int c = i * 512 + t;
      int row = c >> 3, sp = c & 7;
      int col = (sp ^ (row & 7)) << 3;
      g2l16(Bt + (size_t)(nrow0 + h * 128 + row) * KDIM + kt + col,
            &Bs[buf][h * 8192 + c * 8]);
    }
  };

  f32x4 acc[8][4];
#pragma unroll
  for (int i = 0; i < 8; i++)
#pragma unroll
    for (int j = 0; j < 4; j++) acc[i][j] = (f32x4){0.f, 0.f, 0.f, 0.f};

  stageA(0, 0, 0); stageA(0, 0, 1);
  stageB(0, 0, 0); stageB(0, 0, 1);
  stageA(1, 64, 0); stageA(1, 64, 1);
  stageB(1, 64, 0); stageB(1, 64, 1);
  asm volatile("s_waitcnt vmcnt(8)" ::: "memory");
  __builtin_amdgcn_s_barrier();

  const int NT = KDIM / 64;  // 64
  for (int ti = 0; ti < NT; ++ti) {
    const int cur = ti & 1;
    const u16* Asc = As[cur];
    const u16* Bsc = Bs[cur];
    const int ktn2 = (ti + 2) * 64;
    bf16x8 a0[2][4], a1[2][4], b0[2][2], b1[2][2];

    // ---- phase 0: read a0+b0 ; MFMA Q00 ----
#pragma unroll
    for (int kk = 0; kk < 2; kk++)
#pragma unroll
      for (int mi = 0; mi < 4; mi++) {
        int r = wr * 128 + mi * 16 + l15;
        int slot = (kk * 4 + g) ^ (r & 7);
        a0[kk][mi] = *(const bf16x8*)(Asc + r * 64 + slot * 8);
      }
#pragma unroll
    for (int kk = 0; kk < 2; kk++)
#pragma unroll
      for (int ni = 0; ni < 2; ni++) {
        int r = wc * 64 + ni * 16 + l15;
        int slot = (kk * 4 + g) ^ (r & 7);
        b0[kk][ni] = *(const bf16x8*)(Bsc + r * 64 + slot * 8);
      }
    __builtin_amdgcn_s_barrier();
    asm volatile("s_waitcnt lgkmcnt(0)" ::: "memory");
    __builtin_amdgcn_sched_barrier(0);
    __builtin_amdgcn_s_setprio(1);
#pragma unroll
    for (int mi = 0; mi < 4; mi++)
#pragma unroll
      for (int ni = 0; ni < 2; ni++)
#pragma unroll
        for (int kk = 0; kk < 2; kk++)
          acc[mi][ni] = __builtin_amdgcn_mfma_f32_16x16x32_bf16(
              a0[kk][mi], b0[kk][ni], acc[mi][ni], 0, 0, 0);
    __builtin_amdgcn_s_setprio(0);
    __builtin_amdgcn_s_barrier();

    // ---- phase 1: read a1 ; MFMA Q10 ----
#pragma unroll
    for (int kk = 0; kk < 2; kk++)
#pragma unroll
      for (int mi = 0; mi < 4; mi++) {
        int r = wr * 128 + 64 + mi * 16 + l15;
        int slot = (kk * 4 + g) ^ (r & 7);
        a1[kk][mi] = *(const bf16x8*)(Asc + r * 64 + slot * 8);
      }
    __builtin_amdgcn_s_barrier();
    asm volatile("s_waitcnt lgkmcnt(0)" ::: "memory");
    __builtin_amdgcn_sched_barrier(0);
    __builtin_amdgcn_s_setprio(1);
#pragma unroll
    for (int mi = 0; mi < 4; mi++)
#pragma unroll
      for (int ni = 0; ni < 2; ni++)
#pragma unroll
        for (int kk = 0; kk < 2; kk++)
          acc[mi + 4][ni] = __builtin_amdgcn_mfma_f32_16x16x32_bf16(
              a1[kk][mi], b0[kk][ni], acc[mi + 4][ni], 0, 0, 0);
    __builtin_amdgcn_s_setprio(0);
    __builtin_amdgcn_s_barrier();

    // ---- phase 2: read b1 ; stage A(t+2) ; MFMA Q11 ----
#pragma unroll
    for (int kk = 0; kk < 2; kk++)
#pragma unroll
      for (int ni = 0; ni < 2; ni++) {
        int r = wc * 64 + (ni + 2) * 16 + l15;
        int slot = (kk * 4 + g) ^ (r & 7);
        b1[kk][ni] = *(const bf16x8*)(Bsc + r * 64 + slot * 8);
      }
    if (ti + 2 < NT) { stageA(cur, ktn2, 0); stageA(cur, ktn2, 1); }
    __builtin_amdgcn_s_barrier();
    asm volatile("s_waitcnt lgkmcnt(0)" ::: "memory");
    __builtin_amdgcn_sched_barrier(0);
    __builtin_amdgcn_s_setprio(1);
#pragma unroll
    for (int mi = 0; mi < 4; mi++)
#pragma unroll
      for (int ni = 0; ni < 2; ni++)
#pragma unroll
        for (int kk = 0; kk < 2; kk++)
          acc[mi + 4][ni + 2] = __builtin_amdgcn_mfma_f32_16x16x32_bf16(
              a1[kk][mi], b1[kk][ni], acc[mi + 4][ni + 2], 0, 0, 0);
    __builtin_amdgcn_s_setprio(0);
    __builtin_amdgcn_s_barrier();

    // ---- phase 3: stage B(t+2) ; MFMA Q01 ; vmcnt(8) ----
    if (ti + 2 < NT) { stageB(cur, ktn2, 0); stageB(cur, ktn2, 1); }
    __builtin_amdgcn_s_barrier();
    __builtin_amdgcn_s_setprio(1);
#pragma unroll
    for (int mi = 0; mi < 4; mi++)
#pragma unroll
      for (int ni = 0; ni < 2; ni++)
#pragma unroll
        for (int kk = 0; kk < 2; kk++)
          acc[mi][ni + 2] = __builtin_amdgcn_mfma_f32_16x16x32_bf16(
              a0[kk][mi], b1[kk][ni], acc[mi][ni + 2], 0, 0, 0);
    __builtin_amdgcn_s_setprio(0);
    if (ti + 2 < NT)      asm volatile("s_waitcnt vmcnt(8)" ::: "memory");
    else if (ti + 1 < NT) asm volatile("s_waitcnt vmcnt(0)" ::: "memory");
    __builtin_amdgcn_s_barrier();
  }

#pragma unroll
  for (int mi = 0; mi < 8; mi++) {
#pragma unroll
    for (int ni = 0; ni < 4; ni++) {
      int rowg = m0 + wr * 128 + mi * 16 + g * 4;
      int ncol = nb * 256 + wc * 64 + ni * 16 + l15;
      if (nb < 16) {
#pragma unroll
        for (int r = 0; r < 4; r++)
          Qo[(size_t)(rowg + r) * EMBED + ncol] = f2bf(acc[mi][ni][r]);
      } else if (nb < 24) {
        int nc = ncol - 4096;
#pragma unroll
        for (int r = 0; r < 4; r++)
          Ko[(size_t)(rowg + r) * KVW + nc] = f2bf(acc[mi][ni][r]);
      } else {
        int nc = ncol - 6144;  // kv_head*128 + d
        ushort4 v;
        v.x = f2bf(acc[mi][ni][0]); v.y = f2bf(acc[mi][ni][1]);
        v.z = f2bf(acc[mi][ni][2]); v.w = f2bf(acc[mi][ni][3]);
        *(ushort4*)(Vt + (size_t)nc * SEQ + rowg) = v;
      }
    }
  }
}

// ================= out-proj: BM=128 x BN=256, 2-phase/K-tile, f32 out ======
__global__ __launch_bounds__(512, 2) void gemm8_op(
    const u16* __restrict__ A, const u16* __restrict__ Bt,
    float* __restrict__ Cf) {
  __shared__ __align__(16) u16 As[2][128 * 64];
  __shared__ __align__(16) u16 Bs[2][256 * 64];
  const int t = threadIdx.x;
  const int lane = t & 63;
  const int w = t >> 6;
  const int wr = w >> 2;
  const int wc = w & 3;
  const int g = lane >> 4;
  const int l15 = lane & 15;

  const int bid = blockIdx.x;
  const int swz = (bid & 7) * 32 + (bid >> 3);
  const int mb = swz & 15;
  const int nb = swz >> 4;
  const int m0 = mb * 128;
  const int nrow0 = nb * 256;

  auto stageA = [&](int buf, int kt) {
#pragma unroll
    for (int i = 0; i < 2; i++) {
      int c = i * 512 + t;
      int row = c >> 3, sp = c & 7;
      int col = (sp ^ (row & 7)) << 3;
      g2l16(A + (size_t)(m0 + row) * KDIM + kt + col, &As[buf][c * 8]);
    }
  };
  auto stageB = [&](int buf, int kt) {
#pragma unroll
    for (int i = 0; i < 4; i++) {
      int c = i * 512 + t;
      int row = c >> 3, sp = c & 7;
      int col = (sp ^ (row & 7)) << 3;
      g2l16(Bt + (size_t)(nrow0 + row) * KDIM + kt + col, &Bs[buf][c * 8]);
    }
  };

  f32x4 acc[4][4];
#pragma unroll
  for (int i = 0; i < 4; i++)
#pragma unroll
    for (int j = 0; j < 4; j++) acc[i][j] = (f32x4){0.f, 0.f, 0.f, 0.f};

  stageA(0, 0); stageB(0, 0);
  stageA(1, 64); stageB(1, 64);
  asm volatile("s_waitcnt vmcnt(6)" ::: "memory");
  __builtin_amdgcn_s_barrier();

  const int NT = KDIM / 64;
  for (int ti = 0; ti < NT; ++ti) {
    const int cur = ti & 1;
    const u16* Asc = As[cur];
    const u16* Bsc = Bs[cur];
    const int ktn2 = (ti + 2) * 64;
    bf16x8 a[2][4], b0[2][2], b1[2][2];

#pragma unroll
    for (int kk = 0; kk < 2; kk++)
#pragma unroll
      for (int mi = 0; mi < 4; mi++) {
        int r = wr * 64 + mi * 16 + l15;
        int slot = (kk * 4 + g) ^ (r & 7);
        a[kk][mi] = *(const bf16x8*)(Asc + r * 64 + slot * 8);
      }
#pragma unroll
    for (int kk = 0; kk < 2; kk++)
#pragma unroll
      for (int ni = 0; ni < 2; ni++) {
        int r = wc * 64 + ni * 16 + l15;
        int slot = (kk * 4 + g) ^ (r & 7);
        b0[kk][ni] = *(const bf16x8*)(Bsc + r * 64 + slot * 8);
      }
#pragma unroll
    for (int kk = 0; kk < 2; kk++)
#pragma unroll
      for (int ni = 0; ni < 2; ni++) {
        int r = wc * 64 + (ni + 2) * 16 + l15;
        int slot = (kk * 4 + g) ^ (r & 7);
        b1[kk][ni] = *(const bf16x8*)(Bsc + r * 64 + slot * 8);
      }
    __builtin_amdgcn_s_barrier();
    asm volatile("s_waitcnt lgkmcnt(0)" ::: "memory");
    __builtin_amdgcn_sched_barrier(0);
    __builtin_amdgcn_s_setprio(1);
#pragma unroll
    for (int mi = 0; mi < 4; mi++)
#pragma unroll
      for (int ni = 0; ni < 2; ni++)
#pragma unroll
        for (int kk = 0; kk < 2; kk++)
          acc[mi][ni] = __builtin_amdgcn_mfma_f32_16x16x32_bf16(
              a[kk][mi], b0[kk][ni], acc[mi][ni], 0, 0, 0);
    __builtin_amdgcn_s_setprio(0);
    __builtin_amdgcn_s_barrier();

    if (ti + 2 < NT) { stageA(cur, ktn2); stageB(cur, ktn2); }
    __builtin_amdgcn_s_barrier();
    __builtin_amdgcn_s_setprio(1);
#pragma unroll
    for (int mi = 0; mi < 4; mi++)
#pragma unroll
      for (int ni = 0; ni < 2; ni++)
#pragma unroll
        for (int kk = 0; kk < 2; kk++)
          acc[mi][ni + 2] = __builtin_amdgcn_mfma_f32_16x16x32_bf16(
              a[kk][mi], b1[kk][ni], acc[mi][ni + 2], 0, 0, 0);
    __builtin_amdgcn_s_setprio(0);
    if (ti + 2 < NT)      asm volatile("s_waitcnt vmcnt(6)" ::: "memory");
    else if (ti + 1 < NT) asm volatile("s_waitcnt vmcnt(0)" ::: "memory");
    __builtin_amdgcn_s_barrier();
  }

#pragma unroll
  for (int mi = 0; mi < 4; mi++)
#pragma unroll
    for (int ni = 0; ni < 4; ni++) {
      int rowg = m0 + wr * 64 + mi * 16 + g * 4;
      int ncol = nb * 256 + wc * 64 + ni * 16 + l15;
#pragma unroll
      for (int r = 0; r < 4; r++)
        Cf[(size_t)(rowg + r) * 4096 + ncol] = acc[mi][ni][r];
    }
}

// ---------------- RoPE (in place) on K [2048][2048] only ----------------
__global__ __launch_bounds__(256) void rope_k_kernel(
    u16* __restrict__ Kb, const float* __restrict__ freqs,
    const int* __restrict__ start_pos) {
  const int sp = start_pos[0];
  const int total = SEQ * KVW / 2;  // pairs
  for (int idx = blockIdx.x * 256 + threadIdx.x; idx < total;
       idx += gridDim.x * 256) {
    int row = idx >> 10, pi = idx & 1023;
    u16* buf = Kb + (size_t)row * KVW;
    int i = pi & 63;
    float2 cs = *(const float2*)(freqs + (size_t)(sp + row) * 128 + i * 2);
    ushort2 tv = *(ushort2*)(buf + pi * 2);
    float t0 = bf2f(tv.x), t1 = bf2f(tv.y);
    ushort2 o;
    o.x = f2bf(t0 * cs.x - t1 * cs.y);
    o.y = f2bf(t0 * cs.y + t1 * cs.x);
    *(ushort2*)(buf + pi * 2) = o;
  }
}

// ---------------- flash attention, causal, GQA; Q-RoPE fused in-register ---
// Q raw (no rope/scale); K rope'd; Vt transposed. Swapped QK^T softmax.
// NOTE: fragment at slot ps holds d-octet (kk*4+g) (swizzle cancels), so
// freqs index uses (kk*4+g)*8 + 2p — NOT ps.
__global__ __launch_bounds__(256, 4) void attn_kernel(
    const u16* __restrict__ Q, const u16* __restrict__ Kb,
    const u16* __restrict__ Vt, u16* __restrict__ O,
    const float* __restrict__ freqs, const int* __restrict__ start_pos) {
  __shared__ __align__(16) u16 KV[16384];   // K: [0,8192) 64x128, V: [8192,..) 128x64
  __shared__ u16 Ps[4][16 * 72];

  const int t = threadIdx.x;
  const int lane = t & 63;
  const int w = t >> 6;
  const int g = lane >> 4;
  const int l15 = lane & 15;
  const int bid = blockIdx.x;
  const int qb = 31 - (bid >> 5);
  const int h = bid & 31;
  const int hk = h >> 1;

  auto stageK = [&](int kv) {
#pragma unroll
    for (int i = 0; i < 4; i++) {
      int c = i * 256 + t;
      int row = c >> 4, spp = c & 15;
      int col = ((spp ^ (row & 7)) << 3);
      g2l16(Kb + (size_t)(kv * 64 + row) * KVW + hk * HD + col, &KV[c * 8]);
    }
  };
  auto stageV = [&](int kv) {
#pragma unroll
    for (int i = 0; i < 4; i++) {
      int c = i * 256 + t;
      int row = c >> 3, spp = c & 7;
      int col = ((spp ^ (row & 7)) << 3);
      g2l16(Vt + (size_t)(hk * HD + row) * SEQ + kv * 64 + col,
            &KV[8192 + c * 8]);
    }
  };

#pragma unroll
  for (int i = 0; i < 4; i++) {
    int c = i * 256 + t;
    int row = c >> 4, spp = c & 15;
    int col = ((spp ^ (row & 7)) << 3);
    g2l16(Q + (size_t)(qb * 64 + row) * EMBED + h * HD + col, &KV[c * 8]);
  }
  asm volatile("s_waitcnt vmcnt(0)" ::: "memory");
  __builtin_amdgcn_s_barrier();

  // read Q fragments + apply RoPE in-register (pairs are adjacent in d)
  bf16x8 qf[4];
  {
    const int r = w * 16 + l15;
    const int frow = start_pos[0] + qb * 64 + r;
    const float qscale = 0.08838834764831845f;  // 1/sqrt(128)
#pragma unroll
    for (int kk = 0; kk < 4; kk++) {
      int ps = (kk * 4 + g) ^ (r & 7);
      bf16x8 v = *(const bf16x8*)(&KV[r * 128 + ps * 8]);
      bf16x8 o;
      const int d0 = (kk * 4 + g) * 8;   // actual d-octet (swizzle cancels)
#pragma unroll
      for (int p = 0; p < 4; p++) {
        float2 cs = *(const float2*)(freqs + (size_t)frow * 128 + d0 + p * 2);
        float t0 = (float)v[2 * p], t1 = (float)v[2 * p + 1];
        o[2 * p]     = (__bf16)((t0 * cs.x - t1 * cs.y) * qscale);
        o[2 * p + 1] = (__bf16)((t0 * cs.y + t1 * cs.x) * qscale);
      }
      qf[kk] = o;
    }
  }
  asm volatile("s_waitcnt lgkmcnt(0)" ::: "memory");
  __builtin_amdgcn_s_barrier();

  f32x4 oacc[8];
#pragma unroll
  for (int i = 0; i < 8; i++) oacc[i] = (f32x4){0.f, 0.f, 0.f, 0.f};
  float mrow = -1e30f, lrow = 0.f;
  const int qg = qb * 64 + w * 16 + l15;

  for (int kv = 0; kv <= qb; kv++) {
    stageK(kv); stageV(kv);
    asm volatile("s_waitcnt vmcnt(0)" ::: "memory");
    __builtin_amdgcn_s_barrier();

    f32x4 sfragT[4];
    __builtin_amdgcn_s_setprio(1);
#pragma unroll
    for (int ni = 0; ni < 4; ni++) {
      f32x4 s = (f32x4){0.f, 0.f, 0.f, 0.f};
      int r = ni * 16 + l15;
#pragma unroll
      for (int kk = 0; kk < 4; kk++) {
        int ps = (kk * 4 + g) ^ (r & 7);
        bf16x8 a = *(const bf16x8*)(&KV[r * 128 + ps * 8]);
        s = __builtin_amdgcn_mfma_f32_16x16x32_bf16(a, qf[kk], s, 0, 0, 0);
      }
      sfragT[ni] = s;
    }
    __builtin_amdgcn_s_setprio(0);

    if (kv == qb) {
#pragma unroll
      for (int ni = 0; ni < 4; ni++) {
        int colg = kv * 64 + ni * 16 + g * 4;
#pragma unroll
        for (int r = 0; r < 4; r++)
          if (colg + r > qg) sfragT[ni][r] = -1e30f;
      }
    }

    float m16 = sfragT[0][0];
#pragma unroll
    for (int ni = 0; ni < 4; ni++)
#pragma unroll
      for (int r = 0; r < 4; r++) m16 = fmaxf(m16, sfragT[ni][r]);
    m16 = fmaxf(m16, __shfl_xor(m16, 16));
    m16 = fmaxf(m16, __shfl_xor(m16, 32));
    float mnew = fmaxf(mrow, m16);
    float sc = __expf(mrow - mnew);
    mrow = mnew;

    float rsum = 0.f;
#pragma unroll
    for (int ni = 0; ni < 4; ni++) {
#pragma unroll
      for (int r = 0; r < 4; r++) {
        float p = __expf(sfragT[ni][r] - mrow);
        rsum += p;
        Ps[w][l15 * 72 + ni * 16 + g * 4 + r] = f2bf(p);
      }
    }
    rsum += __shfl_xor(rsum, 16);
    rsum += __shfl_xor(rsum, 32);
    lrow = lrow * sc + rsum;

    float scr[4];
#pragma unroll
    for (int r = 0; r < 4; r++) scr[r] = __shfl(sc, g * 4 + r, 64);
#pragma unroll
    for (int nf = 0; nf < 8; nf++)
#pragma unroll
      for (int r = 0; r < 4; r++) oacc[nf][r] *= scr[r];

    asm volatile("s_waitcnt lgkmcnt(0)" ::: "memory");

    bf16x8 pa[2];
#pragma unroll
    for (int kk = 0; kk < 2; kk++)
      pa[kk] = *(const bf16x8*)(&Ps[w][l15 * 72 + kk * 32 + g * 8]);
    __builtin_amdgcn_s_setprio(1);
#pragma unroll
    for (int nf = 0; nf < 8; nf++) {
      int r = nf * 16 + l15;
#pragma unroll
      for (int kk = 0; kk < 2; kk++) {
        int ps = (kk * 4 + g) ^ (r & 7);
        bf16x8 b = *(const bf16x8*)(&KV[8192 + r * 64 + ps * 8]);
        oacc[nf] = __builtin_amdgcn_mfma_f32_16x16x32_bf16(pa[kk], b, oacc[nf], 0, 0, 0);
      }
    }
    __builtin_amdgcn_s_setprio(0);
    __builtin_amdgcn_s_barrier();
  }

  float lr[4];
#pragma unroll
  for (int r = 0; r < 4; r++) lr[r] = __shfl(lrow, g * 4 + r, 64);
#pragma unroll
  for (int nf = 0; nf < 8; nf++) {
#pragma unroll
    for (int r = 0; r < 4; r++) {
      int rowg = qb * 64 + w * 16 + g * 4 + r;
      float v = oacc[nf][r] / lr[r];
      O[(size_t)rowg * EMBED + h * HD + nf * 16 + l15] = f2bf(v);
    }
  }
}

extern "C" void kernel_launch(void* const* d_in, const int* in_sizes, int n_in,
                              void* d_out, int out_size, void* d_ws, size_t ws_size,
                              hipStream_t stream) {
  const float* x  = (const float*)d_in[0];
  const float* fc = (const float*)d_in[1];
  const float* wq = (const float*)d_in[2];
  const float* wk = (const float*)d_in[3];
  const float* wv = (const float*)d_in[4];
  const float* wo = (const float*)d_in[5];
  const int* sp = (const int*)d_in[6];

  char* ws = (char*)d_ws;
  u16* wqT = (u16*)(ws);                      // bf16 [4096][4096]
  u16* wkT = (u16*)(ws + 33554432ull);        // bf16 [2048][4096]
  u16* wvT = (u16*)(ws + 50331648ull);        // bf16 [2048][4096]
  u16* woT = (u16*)(ws + 67108864ull);        // bf16 [4096][4096]
  u16* xb  = (u16*)(ws + 100663296ull);       // bf16 [2048][4096]
  u16* Qb  = (u16*)(ws + 117440512ull);       // bf16 [2048][4096] (raw, no rope)
  u16* Kb  = (u16*)(ws + 134217728ull);       // bf16 [2048][2048]
  u16* Vt  = (u16*)(ws + 142606336ull);       // bf16 [2048][2048]
  u16* Ob  = (u16*)(ws + 150994944ull);       // bf16 [2048][4096]

  prep_kernel<<<dim3(14336), 256, 0, stream>>>(x, xb, wq, wqT, wk, wkT,
                                               wv, wvT, wo, woT);
  gemm8_qkv<<<dim3(256), 512, 0, stream>>>(xb, wqT, wkT, wvT, Qb, Kb, Vt);
  rope_k_kernel<<<dim3(1024), 256, 0, stream>>>(Kb, fc, sp);
  attn_kernel<<<dim3(1024), 256, 0, stream>>>(Qb, Kb, Vt, Ob, fc, sp);
  gemm8_op<<<dim3(256), 512, 0, stream>>>(Ob, woT, (float*)d_out);
}

// Round 13
// 330.819 us; speedup vs baseline: 2.4088x; 1.0513x over previous
//
#include <hip/hip_runtime.h>
#include <stdint.h>

typedef unsigned short u16;
typedef __bf16 bf16x8 __attribute__((ext_vector_type(8)));
typedef float f32x4 __attribute__((ext_vector_type(4)));

#define SEQ   2048
#define EMBED 4096
#define KDIM  4096
#define NH    32
#define NKV   16
#define HD    128
#define KVW   2048   // N_KV_HEADS * HD

__device__ __forceinline__ float bf2f(u16 u) {
  union { uint32_t u; float f; } v; v.u = ((uint32_t)u) << 16; return v.f;
}
__device__ __forceinline__ u16 f2bf(float f) {
  union { float f; uint32_t u; } v; v.f = f;
  return (u16)((v.u + 0x7FFFu + ((v.u >> 16) & 1u)) >> 16);
}
__device__ __forceinline__ void g2l16(const u16* g, u16* l) {
  __builtin_amdgcn_global_load_lds(
      (const __attribute__((address_space(1))) uint32_t*)g,
      (__attribute__((address_space(3))) uint32_t*)l, 16, 0, 0);
}

// ---------------- prep: x f32->bf16 + wq/wk/wv transpose+convert ------------
// (wo transpose moved into attn launch's backfill blocks)
__global__ __launch_bounds__(256) void prep_kernel(
    const float* __restrict__ X, u16* __restrict__ Xb,
    const float* __restrict__ wq, u16* __restrict__ wqT,
    const float* __restrict__ wk, u16* __restrict__ wkT,
    const float* __restrict__ wv, u16* __restrict__ wvT) {
  __shared__ u16 tile[64][68];
  int b = blockIdx.x;
  const int t = threadIdx.x;
  if (b < 2048) {
    const int nquad = SEQ * EMBED / 4;
    for (int i = b * 256 + t; i < nquad; i += 2048 * 256) {
      float4 v = *(const float4*)(X + (size_t)i * 4);
      ushort4 o;
      o.x = f2bf(v.x); o.y = f2bf(v.y); o.z = f2bf(v.z); o.w = f2bf(v.w);
      *(ushort4*)(Xb + (size_t)i * 4) = o;
    }
    return;
  }
  b -= 2048;
  const float* W; u16* Wt; int N, local;
  if (b < 4096)      { W = wq; Wt = wqT; N = 4096; local = b; }
  else if (b < 6144) { W = wk; Wt = wkT; N = 2048; local = b - 4096; }
  else               { W = wv; Wt = wvT; N = 2048; local = b - 6144; }
  const int nx = N >> 6;
  const int n0 = (local % nx) * 64, k0 = (local / nx) * 64;
#pragma unroll
  for (int i = 0; i < 4; i++) {
    int c = i * 256 + t;
    int r = c >> 4, cq = c & 15;
    float4 v = *(const float4*)(W + (size_t)(k0 + r) * N + n0 + cq * 4);
    tile[r][cq * 4 + 0] = f2bf(v.x); tile[r][cq * 4 + 1] = f2bf(v.y);
    tile[r][cq * 4 + 2] = f2bf(v.z); tile[r][cq * 4 + 3] = f2bf(v.w);
  }
  __syncthreads();
#pragma unroll
  for (int i = 0; i < 4; i++) {
    int c = i * 256 + t;
    int rn = c >> 4, cq = c & 15;
    ushort4 v;
    v.x = tile[cq * 4 + 0][rn];
    v.y = tile[cq * 4 + 1][rn];
    v.z = tile[cq * 4 + 2][rn];
    v.w = tile[cq * 4 + 3][rn];
    *(ushort4*)(Wt + (size_t)(n0 + rn) * KDIM + k0 + cq * 4) = v;
  }
}

// ================= 256x256 GEMM for QKV (round-6 schedule, plain epilogue) ==
__global__ __launch_bounds__(512, 2) void gemm8_qkv(
    const u16* __restrict__ A,
    const u16* __restrict__ B0, const u16* __restrict__ B1,
    const u16* __restrict__ B2,
    u16* __restrict__ Qo, u16* __restrict__ Ko, u16* __restrict__ Vt) {
  __shared__ __align__(16) u16 As[2][256 * 64];
  __shared__ __align__(16) u16 Bs[2][256 * 64];
  const int t = threadIdx.x;
  const int lane = t & 63;
  const int w = t >> 6;
  const int wr = w >> 2;
  const int wc = w & 3;
  const int g = lane >> 4;
  const int l15 = lane & 15;

  const int bid = blockIdx.x;
  const int swz = (bid & 7) * 32 + (bid >> 3);
  const int mb = swz & 7;
  const int nb = swz >> 3;
  const int m0 = mb * 256;

  const u16* Bt; int nrow0;
  if (nb < 16)      { Bt = B0; nrow0 = nb * 256; }
  else if (nb < 24) { Bt = B1; nrow0 = (nb - 16) * 256; }
  else              { Bt = B2; nrow0 = (nb - 24) * 256; }

  auto stageA = [&](int buf, int kt, int h) {
#pragma unroll
    for (int i = 0; i < 2; i++) {
      int c = i * 512 + t;
      int row = c >> 3, sp = c & 7;
      int col = (sp ^ (row & 7)) << 3;
      g2l16(A + (size_t)(m0 + h * 128 + row) * KDIM + kt + col,
            &As[buf][h * 8192 + c * 8]);
    }
  };
  auto stageB = [&](int buf, int kt, int h) {
#pragma unroll
    for (int i = 0; i < 2; i++) {
      int c = i * 512 + t;
      int row = c >> 3, sp = c & 7;
      int col = (sp ^ (row & 7)) << 3;
      g2l16(Bt + (size_t)(nrow0 + h * 128 + row) * KDIM + kt + col,
            &Bs[buf][h * 8192 + c * 8]);
    }
  };

  f32x4 acc[8][4];
#pragma unroll
  for (int i = 0; i < 8; i++)
#pragma unroll
    for (int j = 0; j < 4; j++) acc[i][j] = (f32x4){0.f, 0.f, 0.f, 0.f};

  stageA(0, 0, 0); stageA(0, 0, 1);
  stageB(0, 0, 0); stageB(0, 0, 1);
  stageA(1, 64, 0); stageA(1, 64, 1);
  stageB(1, 64, 0); stageB(1, 64, 1);
  asm volatile("s_waitcnt vmcnt(8)" ::: "memory");
  __builtin_amdgcn_s_barrier();

  const int NT = KDIM / 64;  // 64
  for (int ti = 0; ti < NT; ++ti) {
    const int cur = ti & 1;
    const u16* Asc = As[cur];
    const u16* Bsc = Bs[cur];
    const int ktn2 = (ti + 2) * 64;
    bf16x8 a0[2][4], a1[2][4], b0[2][2], b1[2][2];

    // ---- phase 0: read a0+b0 ; MFMA Q00 ----
#pragma unroll
    for (int kk = 0; kk < 2; kk++)
#pragma unroll
      for (int mi = 0; mi < 4; mi++) {
        int r = wr * 128 + mi * 16 + l15;
        int slot = (kk * 4 + g) ^ (r & 7);
        a0[kk][mi] = *(const bf16x8*)(Asc + r * 64 + slot * 8);
      }
#pragma unroll
    for (int kk = 0; kk < 2; kk++)
#pragma unroll
      for (int ni = 0; ni < 2; ni++) {
        int r = wc * 64 + ni * 16 + l15;
        int slot = (kk * 4 + g) ^ (r & 7);
        b0[kk][ni] = *(const bf16x8*)(Bsc + r * 64 + slot * 8);
      }
    __builtin_amdgcn_s_barrier();
    asm volatile("s_waitcnt lgkmcnt(0)" ::: "memory");
    __builtin_amdgcn_sched_barrier(0);
    __builtin_amdgcn_s_setprio(1);
#pragma unroll
    for (int mi = 0; mi < 4; mi++)
#pragma unroll
      for (int ni = 0; ni < 2; ni++)
#pragma unroll
        for (int kk = 0; kk < 2; kk++)
          acc[mi][ni] = __builtin_amdgcn_mfma_f32_16x16x32_bf16(
              a0[kk][mi], b0[kk][ni], acc[mi][ni], 0, 0, 0);
    __builtin_amdgcn_s_setprio(0);
    __builtin_amdgcn_s_barrier();

    // ---- phase 1: read a1 ; MFMA Q10 ----
#pragma unroll
    for (int kk = 0; kk < 2; kk++)
#pragma unroll
      for (int mi = 0; mi < 4; mi++) {
        int r = wr * 128 + 64 + mi * 16 + l15;
        int slot = (kk * 4 + g) ^ (r & 7);
        a1[kk][mi] = *(const bf16x8*)(Asc + r * 64 + slot * 8);
      }
    __builtin_amdgcn_s_barrier();
    asm volatile("s_waitcnt lgkmcnt(0)" ::: "memory");
    __builtin_amdgcn_sched_barrier(0);
    __builtin_amdgcn_s_setprio(1);
#pragma unroll
    for (int mi = 0; mi < 4; mi++)
#pragma unroll
      for (int ni = 0; ni < 2; ni++)
#pragma unroll
        for (int kk = 0; kk < 2; kk++)
          acc[mi + 4][ni] = __builtin_amdgcn_mfma_f32_16x16x32_bf16(
              a1[kk][mi], b0[kk][ni], acc[mi + 4][ni], 0, 0, 0);
    __builtin_amdgcn_s_setprio(0);
    __builtin_amdgcn_s_barrier();

    // ---- phase 2: read b1 ; stage A(t+2) ; MFMA Q11 ----
#pragma unroll
    for (int kk = 0; kk < 2; kk++)
#pragma unroll
      for (int ni = 0; ni < 2; ni++) {
        int r = wc * 64 + (ni + 2) * 16 + l15;
        int slot = (kk * 4 + g) ^ (r & 7);
        b1[kk][ni] = *(const bf16x8*)(Bsc + r * 64 + slot * 8);
      }
    if (ti + 2 < NT) { stageA(cur, ktn2, 0); stageA(cur, ktn2, 1); }
    __builtin_amdgcn_s_barrier();
    asm volatile("s_waitcnt lgkmcnt(0)" ::: "memory");
    __builtin_amdgcn_sched_barrier(0);
    __builtin_amdgcn_s_setprio(1);
#pragma unroll
    for (int mi = 0; mi < 4; mi++)
#pragma unroll
      for (int ni = 0; ni < 2; ni++)
#pragma unroll
        for (int kk = 0; kk < 2; kk++)
          acc[mi + 4][ni + 2] = __builtin_amdgcn_mfma_f32_16x16x32_bf16(
              a1[kk][mi], b1[kk][ni], acc[mi + 4][ni + 2], 0, 0, 0);
    __builtin_amdgcn_s_setprio(0);
    __builtin_amdgcn_s_barrier();

    // ---- phase 3: stage B(t+2) ; MFMA Q01 ; vmcnt(8) ----
    if (ti + 2 < NT) { stageB(cur, ktn2, 0); stageB(cur, ktn2, 1); }
    __builtin_amdgcn_s_barrier();
    __builtin_amdgcn_s_setprio(1);
#pragma unroll
    for (int mi = 0; mi < 4; mi++)
#pragma unroll
      for (int ni = 0; ni < 2; ni++)
#pragma unroll
        for (int kk = 0; kk < 2; kk++)
          acc[mi][ni + 2] = __builtin_amdgcn_mfma_f32_16x16x32_bf16(
              a0[kk][mi], b1[kk][ni], acc[mi][ni + 2], 0, 0, 0);
    __builtin_amdgcn_s_setprio(0);
    if (ti + 2 < NT)      asm volatile("s_waitcnt vmcnt(8)" ::: "memory");
    else if (ti + 1 < NT) asm volatile("s_waitcnt vmcnt(0)" ::: "memory");
    __builtin_amdgcn_s_barrier();
  }

#pragma unroll
  for (int mi = 0; mi < 8; mi++) {
#pragma unroll
    for (int ni = 0; ni < 4; ni++) {
      int rowg = m0 + wr * 128 + mi * 16 + g * 4;
      int ncol = nb * 256 + wc * 64 + ni * 16 + l15;
      if (nb < 16) {
#pragma unroll
        for (int r = 0; r < 4; r++)
          Qo[(size_t)(rowg + r) * EMBED + ncol] = f2bf(acc[mi][ni][r]);
      } else if (nb < 24) {
        int nc = ncol - 4096;
#pragma unroll
        for (int r = 0; r < 4; r++)
          Ko[(size_t)(rowg + r) * KVW + nc] = f2bf(acc[mi][ni][r]);
      } else {
        int nc = ncol - 6144;  // kv_head*128 + d
        ushort4 v;
        v.x = f2bf(acc[mi][ni][0]); v.y = f2bf(acc[mi][ni][1]);
        v.z = f2bf(acc[mi][ni][2]); v.w = f2bf(acc[mi][ni][3]);
        *(ushort4*)(Vt + (size_t)nc * SEQ + rowg) = v;
      }
    }
  }
}

// ================= out-proj: BM=128 x BN=256, 2-phase/K-tile, f32 out ======
__global__ __launch_bounds__(512, 2) void gemm8_op(
    const u16* __restrict__ A, const u16* __restrict__ Bt,
    float* __restrict__ Cf) {
  __shared__ __align__(16) u16 As[2][128 * 64];
  __shared__ __align__(16) u16 Bs[2][256 * 64];
  const int t = threadIdx.x;
  const int lane = t & 63;
  const int w = t >> 6;
  const int wr = w >> 2;
  const int wc = w & 3;
  const int g = lane >> 4;
  const int l15 = lane & 15;

  const int bid = blockIdx.x;
  const int swz = (bid & 7) * 32 + (bid >> 3);
  const int mb = swz & 15;
  const int nb = swz >> 4;
  const int m0 = mb * 128;
  const int nrow0 = nb * 256;

  auto stageA = [&](int buf, int kt) {
#pragma unroll
    for (int i = 0; i < 2; i++) {
      int c = i * 512 + t;
      int row = c >> 3, sp = c & 7;
      int col = (sp ^ (row & 7)) << 3;
      g2l16(A + (size_t)(m0 + row) * KDIM + kt + col, &As[buf][c * 8]);
    }
  };
  auto stageB = [&](int buf, int kt) {
#pragma unroll
    for (int i = 0; i < 4; i++) {
      int c = i * 512 + t;
      int row = c >> 3, sp = c & 7;
      int col = (sp ^ (row & 7)) << 3;
      g2l16(Bt + (size_t)(nrow0 + row) * KDIM + kt + col, &Bs[buf][c * 8]);
    }
  };

  f32x4 acc[4][4];
#pragma unroll
  for (int i = 0; i < 4; i++)
#pragma unroll
    for (int j = 0; j < 4; j++) acc[i][j] = (f32x4){0.f, 0.f, 0.f, 0.f};

  stageA(0, 0); stageB(0, 0);
  stageA(1, 64); stageB(1, 64);
  asm volatile("s_waitcnt vmcnt(6)" ::: "memory");
  __builtin_amdgcn_s_barrier();

  const int NT = KDIM / 64;
  for (int ti = 0; ti < NT; ++ti) {
    const int cur = ti & 1;
    const u16* Asc = As[cur];
    const u16* Bsc = Bs[cur];
    const int ktn2 = (ti + 2) * 64;
    bf16x8 a[2][4], b0[2][2], b1[2][2];

#pragma unroll
    for (int kk = 0; kk < 2; kk++)
#pragma unroll
      for (int mi = 0; mi < 4; mi++) {
        int r = wr * 64 + mi * 16 + l15;
        int slot = (kk * 4 + g) ^ (r & 7);
        a[kk][mi] = *(const bf16x8*)(Asc + r * 64 + slot * 8);
      }
#pragma unroll
    for (int kk = 0; kk < 2; kk++)
#pragma unroll
      for (int ni = 0; ni < 2; ni++) {
        int r = wc * 64 + ni * 16 + l15;
        int slot = (kk * 4 + g) ^ (r & 7);
        b0[kk][ni] = *(const bf16x8*)(Bsc + r * 64 + slot * 8);
      }
#pragma unroll
    for (int kk = 0; kk < 2; kk++)
#pragma unroll
      for (int ni = 0; ni < 2; ni++) {
        int r = wc * 64 + (ni + 2) * 16 + l15;
        int slot = (kk * 4 + g) ^ (r & 7);
        b1[kk][ni] = *(const bf16x8*)(Bsc + r * 64 + slot * 8);
      }
    __builtin_amdgcn_s_barrier();
    asm volatile("s_waitcnt lgkmcnt(0)" ::: "memory");
    __builtin_amdgcn_sched_barrier(0);
    __builtin_amdgcn_s_setprio(1);
#pragma unroll
    for (int mi = 0; mi < 4; mi++)
#pragma unroll
      for (int ni = 0; ni < 2; ni++)
#pragma unroll
        for (int kk = 0; kk < 2; kk++)
          acc[mi][ni] = __builtin_amdgcn_mfma_f32_16x16x32_bf16(
              a[kk][mi], b0[kk][ni], acc[mi][ni], 0, 0, 0);
    __builtin_amdgcn_s_setprio(0);
    __builtin_amdgcn_s_barrier();

    if (ti + 2 < NT) { stageA(cur, ktn2); stageB(cur, ktn2); }
    __builtin_amdgcn_s_barrier();
    __builtin_amdgcn_s_setprio(1);
#pragma unroll
    for (int mi = 0; mi < 4; mi++)
#pragma unroll
      for (int ni = 0; ni < 2; ni++)
#pragma unroll
        for (int kk = 0; kk < 2; kk++)
          acc[mi][ni + 2] = __builtin_amdgcn_mfma_f32_16x16x32_bf16(
              a[kk][mi], b1[kk][ni], acc[mi][ni + 2], 0, 0, 0);
    __builtin_amdgcn_s_setprio(0);
    if (ti + 2 < NT)      asm volatile("s_waitcnt vmcnt(6)" ::: "memory");
    else if (ti + 1 < NT) asm volatile("s_waitcnt vmcnt(0)" ::: "memory");
    __builtin_amdgcn_s_barrier();
  }

#pragma unroll
  for (int mi = 0; mi < 4; mi++)
#pragma unroll
    for (int ni = 0; ni < 4; ni++) {
      int rowg = m0 + wr * 64 + mi * 16 + g * 4;
      int ncol = nb * 256 + wc * 64 + ni * 16 + l15;
#pragma unroll
      for (int r = 0; r < 4; r++)
        Cf[(size_t)(rowg + r) * 4096 + ncol] = acc[mi][ni][r];
    }
}

// ---------------- RoPE (in place) on K [2048][2048] only ----------------
__global__ __launch_bounds__(256) void rope_k_kernel(
    u16* __restrict__ Kb, const float* __restrict__ freqs,
    const int* __restrict__ start_pos) {
  const int sp = start_pos[0];
  const int total = SEQ * KVW / 2;  // pairs
  for (int idx = blockIdx.x * 256 + threadIdx.x; idx < total;
       idx += gridDim.x * 256) {
    int row = idx >> 10, pi = idx & 1023;
    u16* buf = Kb + (size_t)row * KVW;
    int i = pi & 63;
    float2 cs = *(const float2*)(freqs + (size_t)(sp + row) * 128 + i * 2);
    ushort2 tv = *(ushort2*)(buf + pi * 2);
    float t0 = bf2f(tv.x), t1 = bf2f(tv.y);
    ushort2 o;
    o.x = f2bf(t0 * cs.x - t1 * cs.y);
    o.y = f2bf(t0 * cs.y + t1 * cs.x);
    *(ushort2*)(buf + pi * 2) = o;
  }
}

// ---------------- flash attention + wo-transpose backfill -------------------
// blocks [0,1024): attn (Q-RoPE fused in-register; swapped QK^T softmax).
// blocks [1024,5120): wo f32[4096][4096] -> woT bf16[4096][4096] transpose,
// backfilling the attn tail (LDS aliased onto KV buffer).
__global__ __launch_bounds__(256, 4) void attn_kernel(
    const u16* __restrict__ Q, const u16* __restrict__ Kb,
    const u16* __restrict__ Vt, u16* __restrict__ O,
    const float* __restrict__ freqs, const int* __restrict__ start_pos,
    const float* __restrict__ wo, u16* __restrict__ woT) {
  __shared__ __align__(16) u16 KV[16384];   // K: [0,8192) 64x128, V: [8192,..) 128x64
  __shared__ u16 Ps[4][16 * 72];

  const int t = threadIdx.x;
  const int bid = blockIdx.x;

  if (bid >= 1024) {  // ---- wo transpose tile ----
    u16 (*tile)[68] = (u16(*)[68])KV;   // alias: 8.7 KB inside 32 KB buffer
    const int local = bid - 1024;       // 0..4095
    const int n0 = (local & 63) * 64, k0 = (local >> 6) * 64;
#pragma unroll
    for (int i = 0; i < 4; i++) {
      int c = i * 256 + t;
      int r = c >> 4, cq = c & 15;
      float4 v = *(const float4*)(wo + (size_t)(k0 + r) * 4096 + n0 + cq * 4);
      tile[r][cq * 4 + 0] = f2bf(v.x); tile[r][cq * 4 + 1] = f2bf(v.y);
      tile[r][cq * 4 + 2] = f2bf(v.z); tile[r][cq * 4 + 3] = f2bf(v.w);
    }
    __syncthreads();
#pragma unroll
    for (int i = 0; i < 4; i++) {
      int c = i * 256 + t;
      int rn = c >> 4, cq = c & 15;
      ushort4 v;
      v.x = tile[cq * 4 + 0][rn];
      v.y = tile[cq * 4 + 1][rn];
      v.z = tile[cq * 4 + 2][rn];
      v.w = tile[cq * 4 + 3][rn];
      *(ushort4*)(woT + (size_t)(n0 + rn) * KDIM + k0 + cq * 4) = v;
    }
    return;
  }

  const int lane = t & 63;
  const int w = t >> 6;
  const int g = lane >> 4;
  const int l15 = lane & 15;
  const int qb = 31 - (bid >> 5);
  const int h = bid & 31;
  const int hk = h >> 1;

  auto stageK = [&](int kv) {
#pragma unroll
    for (int i = 0; i < 4; i++) {
      int c = i * 256 + t;
      int row = c >> 4, spp = c & 15;
      int col = ((spp ^ (row & 7)) << 3);
      g2l16(Kb + (size_t)(kv * 64 + row) * KVW + hk * HD + col, &KV[c * 8]);
    }
  };
  auto stageV = [&](int kv) {
#pragma unroll
    for (int i = 0; i < 4; i++) {
      int c = i * 256 + t;
      int row = c >> 3, spp = c & 7;
      int col = ((spp ^ (row & 7)) << 3);
      g2l16(Vt + (size_t)(hk * HD + row) * SEQ + kv * 64 + col,
            &KV[8192 + c * 8]);
    }
  };

#pragma unroll
  for (int i = 0; i < 4; i++) {
    int c = i * 256 + t;
    int row = c >> 4, spp = c & 15;
    int col = ((spp ^ (row & 7)) << 3);
    g2l16(Q + (size_t)(qb * 64 + row) * EMBED + h * HD + col, &KV[c * 8]);
  }
  asm volatile("s_waitcnt vmcnt(0)" ::: "memory");
  __builtin_amdgcn_s_barrier();

  // read Q fragments + apply RoPE in-register
  bf16x8 qf[4];
  {
    const int r = w * 16 + l15;
    const int frow = start_pos[0] + qb * 64 + r;
    const float qscale = 0.08838834764831845f;  // 1/sqrt(128)
#pragma unroll
    for (int kk = 0; kk < 4; kk++) {
      int ps = (kk * 4 + g) ^ (r & 7);
      bf16x8 v = *(const bf16x8*)(&KV[r * 128 + ps * 8]);
      bf16x8 o;
      const int d0 = (kk * 4 + g) * 8;   // actual d-octet (swizzle cancels)
#pragma unroll
      for (int p = 0; p < 4; p++) {
        float2 cs = *(const float2*)(freqs + (size_t)frow * 128 + d0 + p * 2);
        float t0 = (float)v[2 * p], t1 = (float)v[2 * p + 1];
        o[2 * p]     = (__bf16)((t0 * cs.x - t1 * cs.y) * qscale);
        o[2 * p + 1] = (__bf16)((t0 * cs.y + t1 * cs.x) * qscale);
      }
      qf[kk] = o;
    }
  }
  asm volatile("s_waitcnt lgkmcnt(0)" ::: "memory");
  __builtin_amdgcn_s_barrier();

  f32x4 oacc[8];
#pragma unroll
  for (int i = 0; i < 8; i++) oacc[i] = (f32x4){0.f, 0.f, 0.f, 0.f};
  float mrow = -1e30f, lrow = 0.f;
  const int qg = qb * 64 + w * 16 + l15;

  for (int kv = 0; kv <= qb; kv++) {
    stageK(kv); stageV(kv);
    asm volatile("s_waitcnt vmcnt(0)" ::: "memory");
    __builtin_amdgcn_s_barrier();

    f32x4 sfragT[4];
    __builtin_amdgcn_s_setprio(1);
#pragma unroll
    for (int ni = 0; ni < 4; ni++) {
      f32x4 s = (f32x4){0.f, 0.f, 0.f, 0.f};
      int r = ni * 16 + l15;
#pragma unroll
      for (int kk = 0; kk < 4; kk++) {
        int ps = (kk * 4 + g) ^ (r & 7);
        bf16x8 a = *(const bf16x8*)(&KV[r * 128 + ps * 8]);
        s = __builtin_amdgcn_mfma_f32_16x16x32_bf16(a, qf[kk], s, 0, 0, 0);
      }
      sfragT[ni] = s;
    }
    __builtin_amdgcn_s_setprio(0);

    if (kv == qb) {
#pragma unroll
      for (int ni = 0; ni < 4; ni++) {
        int colg = kv * 64 + ni * 16 + g * 4;
#pragma unroll
        for (int r = 0; r < 4; r++)
          if (colg + r > qg) sfragT[ni][r] = -1e30f;
      }
    }

    float m16 = sfragT[0][0];
#pragma unroll
    for (int ni = 0; ni < 4; ni++)
#pragma unroll
      for (int r = 0; r < 4; r++) m16 = fmaxf(m16, sfragT[ni][r]);
    m16 = fmaxf(m16, __shfl_xor(m16, 16));
    m16 = fmaxf(m16, __shfl_xor(m16, 32));
    float mnew = fmaxf(mrow, m16);
    float sc = __expf(mrow - mnew);
    mrow = mnew;

    float rsum = 0.f;
#pragma unroll
    for (int ni = 0; ni < 4; ni++) {
#pragma unroll
      for (int r = 0; r < 4; r++) {
        float p = __expf(sfragT[ni][r] - mrow);
        rsum += p;
        Ps[w][l15 * 72 + ni * 16 + g * 4 + r] = f2bf(p);
      }
    }
    rsum += __shfl_xor(rsum, 16);
    rsum += __shfl_xor(rsum, 32);
    lrow = lrow * sc + rsum;

    float scr[4];
#pragma unroll
    for (int r = 0; r < 4; r++) scr[r] = __shfl(sc, g * 4 + r, 64);
#pragma unroll
    for (int nf = 0; nf < 8; nf++)
#pragma unroll
      for (int r = 0; r < 4; r++) oacc[nf][r] *= scr[r];

    asm volatile("s_waitcnt lgkmcnt(0)" ::: "memory");

    bf16x8 pa[2];
#pragma unroll
    for (int kk = 0; kk < 2; kk++)
      pa[kk] = *(const bf16x8*)(&Ps[w][l15 * 72 + kk * 32 + g * 8]);
    __builtin_amdgcn_s_setprio(1);
#pragma unroll
    for (int nf = 0; nf < 8; nf++) {
      int r = nf * 16 + l15;
#pragma unroll
      for (int kk = 0; kk < 2; kk++) {
        int ps = (kk * 4 + g) ^ (r & 7);
        bf16x8 b = *(const bf16x8*)(&KV[8192 + r * 64 + ps * 8]);
        oacc[nf] = __builtin_amdgcn_mfma_f32_16x16x32_bf16(pa[kk], b, oacc[nf], 0, 0, 0);
      }
    }
    __builtin_amdgcn_s_setprio(0);
    __builtin_amdgcn_s_barrier();
  }

  float lr[4];
#pragma unroll
  for (int r = 0; r < 4; r++) lr[r] = __shfl(lrow, g * 4 + r, 64);
#pragma unroll
  for (int nf = 0; nf < 8; nf++) {
#pragma unroll
    for (int r = 0; r < 4; r++) {
      int rowg = qb * 64 + w * 16 + g * 4 + r;
      float v = oacc[nf][r] / lr[r];
      O[(size_t)rowg * EMBED + h * HD + nf * 16 + l15] = f2bf(v);
    }
  }
}

extern "C" void kernel_launch(void* const* d_in, const int* in_sizes, int n_in,
                              void* d_out, int out_size, void* d_ws, size_t ws_size,
                              hipStream_t stream) {
  const float* x  = (const float*)d_in[0];
  const float* fc = (const float*)d_in[1];
  const float* wq = (const float*)d_in[2];
  const float* wk = (const float*)d_in[3];
  const float* wv = (const float*)d_in[4];
  const float* wo = (const float*)d_in[5];
  const int* sp = (const int*)d_in[6];

  char* ws = (char*)d_ws;
  u16* wqT = (u16*)(ws);                      // bf16 [4096][4096]
  u16* wkT = (u16*)(ws + 33554432ull);        // bf16 [2048][4096]
  u16* wvT = (u16*)(ws + 50331648ull);        // bf16 [2048][4096]
  u16* woT = (u16*)(ws + 67108864ull);        // bf16 [4096][4096]
  u16* xb  = (u16*)(ws + 100663296ull);       // bf16 [2048][4096]
  u16* Qb  = (u16*)(ws + 117440512ull);       // bf16 [2048][4096] (raw, no rope)
  u16* Kb  = (u16*)(ws + 134217728ull);       // bf16 [2048][2048]
  u16* Vt  = (u16*)(ws + 142606336ull);       // bf16 [2048][2048]
  u16* Ob  = (u16*)(ws + 150994944ull);       // bf16 [2048][4096]

  prep_kernel<<<dim3(10240), 256, 0, stream>>>(x, xb, wq, wqT, wk, wkT,
                                               wv, wvT);
  gemm8_qkv<<<dim3(256), 512, 0, stream>>>(xb, wqT, wkT, wvT, Qb, Kb, Vt);
  rope_k_kernel<<<dim3(1024), 256, 0, stream>>>(Kb, fc, sp);
  attn_kernel<<<dim3(5120), 256, 0, stream>>>(Qb, Kb, Vt, Ob, fc, sp,
                                              wo, woT);
  gemm8_op<<<dim3(256), 512, 0, stream>>>(Ob, woT, (float*)d_out);
}